// Round 8
// baseline (789.271 us; speedup 1.0000x reference)
//
#include <hip/hip_runtime.h>

#define NN 50000
#define EE 150000
#define BN_EPS 1e-5f
#define SLOPE 0.01f
#define SCAN_B 196          // ceil((NN+1)/256)
#define AGG_B  1563         // ceil(NN/32)

// ---------------- CSR build ----------------
__global__ __launch_bounds__(256) void k_count(const int* __restrict__ ei, int* __restrict__ cnt) {
    int e = blockIdx.x * blockDim.x + threadIdx.x;
    if (e < EE) atomicAdd(&cnt[ei[EE + e]], 1);
}

__global__ __launch_bounds__(256) void k_scanA(const int* __restrict__ cnt,
                                               int* __restrict__ rowptr,
                                               int* __restrict__ bsum) {
    __shared__ int buf[256];
    int t = threadIdx.x;
    int idx = blockIdx.x * 256 + t;
    int v = (idx <= NN) ? cnt[idx] : 0;
    buf[t] = v;
    __syncthreads();
    for (int off = 1; off < 256; off <<= 1) {
        int add = (t >= off) ? buf[t - off] : 0;
        __syncthreads();
        buf[t] += add;
        __syncthreads();
    }
    if (idx <= NN) rowptr[idx] = buf[t] - v;
    if (t == 255) bsum[blockIdx.x] = buf[255];
}

__global__ __launch_bounds__(256) void k_scanB(int* __restrict__ bsum) {
    __shared__ int buf[256];
    int t = threadIdx.x;
    int v = (t < SCAN_B) ? bsum[t] : 0;
    buf[t] = v;
    __syncthreads();
    for (int off = 1; off < 256; off <<= 1) {
        int add = (t >= off) ? buf[t - off] : 0;
        __syncthreads();
        buf[t] += add;
        __syncthreads();
    }
    if (t < SCAN_B) bsum[t] = buf[t] - v;
}

__global__ __launch_bounds__(256) void k_scanC(int* __restrict__ rowptr,
                                               int* __restrict__ cursor,
                                               const int* __restrict__ bsum) {
    int idx = blockIdx.x * 256 + threadIdx.x;
    if (idx <= NN) {
        int r = rowptr[idx] + bsum[blockIdx.x];
        rowptr[idx] = r;
        cursor[idx] = r;
    }
}

__global__ __launch_bounds__(256) void k_fill(const int* __restrict__ ei,
                                              int* __restrict__ cursor,
                                              int* __restrict__ perm) {
    int e = blockIdx.x * blockDim.x + threadIdx.x;
    if (e < EE) perm[e] = atomicAdd(&cursor[ei[EE + e]], 1);
}

// in-block BN finalize: stats -> scale/shift in LDS (caller syncs)
__device__ __forceinline__ void bn_scsh(const float* __restrict__ stats,
                                        const float* __restrict__ gamma,
                                        const float* __restrict__ beta,
                                        int flag, float* sc, float* sh) {
    if (flag && threadIdx.x < 32) {
        int o = threadIdx.x;
        float mu = stats[o] * (1.0f / NN);
        float var = stats[32 + o] * (1.0f / NN) - mu * mu;
        float s = gamma[o] * rsqrtf(var + BN_EPS);
        sc[o] = s;
        sh[o] = fmaf(-mu, s, beta[o]);
    }
}

// ---------------- per-layer kernels ----------------
// 2 edges/thread; weights LDS-staged; h read through fused BN+leakyrelu
__global__ __launch_bounds__(256, 2) void k_msg(
    const float* __restrict__ h, const int* __restrict__ ei,
    const float* __restrict__ ea, const float* __restrict__ W1,
    const float* __restrict__ b1, const float* __restrict__ W2,
    const float* __restrict__ b2,
    const float* __restrict__ stats, const float* __restrict__ gamma,
    const float* __restrict__ beta, int flag,
    const int* __restrict__ perm, float* __restrict__ m)
{
    __shared__ float4 sw[2816];          // 11 x 1024 floats: W2[0..9], b2 as #10 (45 KB)
    __shared__ float sc[32], sh[32];

    int t = threadIdx.x;
    const float4* W2v = (const float4*)W2;
#pragma unroll
    for (int j = 0; j < 10; ++j) sw[j * 256 + t] = W2v[j * 256 + t];
    sw[2560 + t] = ((const float4*)b2)[t];
    bn_scsh(stats, gamma, beta, flag, sc, sh);
    __syncthreads();

    int e0 = blockIdx.x * 512 + t;
    int e1 = e0 + 256;
    bool v0 = e0 < EE, v1 = e1 < EE;
    int s0 = v0 ? ei[e0] : 0;
    int s1 = v1 ? ei[e1] : 0;
    float2 a0 = v0 ? ((const float2*)ea)[e0] : make_float2(0.f, 0.f);
    float2 a1 = v1 ? ((const float2*)ea)[e1] : make_float2(0.f, 0.f);
    int p0 = v0 ? perm[e0] : 0;
    int p1 = v1 ? perm[e1] : 0;

    float ek0[11], ek1[11];
#pragma unroll
    for (int k = 0; k < 10; ++k) {
        float w1a = W1[k], w1b = W1[10 + k], bb = b1[k];
        ek0[k] = fmaxf(fmaf(a0.x, w1a, fmaf(a0.y, w1b, bb)), 0.0f);
        ek1[k] = fmaxf(fmaf(a1.x, w1a, fmaf(a1.y, w1b, bb)), 0.0f);
    }
    ek0[10] = 1.0f; ek1[10] = 1.0f;

    float hv0[32], hv1[32];
    const float4* hp0 = (const float4*)(h + s0 * 32);
    const float4* hp1 = (const float4*)(h + s1 * 32);
#pragma unroll
    for (int q = 0; q < 8; ++q) {
        float4 ta = hp0[q], tb = hp1[q];
        hv0[4 * q] = ta.x; hv0[4 * q + 1] = ta.y; hv0[4 * q + 2] = ta.z; hv0[4 * q + 3] = ta.w;
        hv1[4 * q] = tb.x; hv1[4 * q + 1] = tb.y; hv1[4 * q + 2] = tb.z; hv1[4 * q + 3] = tb.w;
    }
    if (flag) {
#pragma unroll
        for (int i = 0; i < 32; ++i) {
            float y0 = fmaf(hv0[i], sc[i], sh[i]);
            float y1 = fmaf(hv1[i], sc[i], sh[i]);
            hv0[i] = y0 > 0.f ? y0 : SLOPE * y0;
            hv1[i] = y1 > 0.f ? y1 : SLOPE * y1;
        }
    }

    float4 acc0[8], acc1[8];
#pragma unroll
    for (int o = 0; o < 8; ++o) {
        acc0[o] = make_float4(0.f, 0.f, 0.f, 0.f);
        acc1[o] = make_float4(0.f, 0.f, 0.f, 0.f);
    }

    for (int k = 0; k < 11; ++k) {           // rolled: keeps body I$-safe
        float ekk0 = ek0[k], ekk1 = ek1[k];
        const float4* wk = &sw[k * 256];
#pragma unroll
        for (int i = 0; i < 32; ++i) {
            float z0 = ekk0 * hv0[i];
            float z1 = ekk1 * hv1[i];
            const float4* wr = wk + i * 8;
#pragma unroll
            for (int o = 0; o < 8; ++o) {
                float4 wv = wr[o];           // wave-uniform ds_read_b128 broadcast
                acc0[o].x = fmaf(z0, wv.x, acc0[o].x);
                acc0[o].y = fmaf(z0, wv.y, acc0[o].y);
                acc0[o].z = fmaf(z0, wv.z, acc0[o].z);
                acc0[o].w = fmaf(z0, wv.w, acc0[o].w);
                acc1[o].x = fmaf(z1, wv.x, acc1[o].x);
                acc1[o].y = fmaf(z1, wv.y, acc1[o].y);
                acc1[o].z = fmaf(z1, wv.z, acc1[o].z);
                acc1[o].w = fmaf(z1, wv.w, acc1[o].w);
            }
        }
    }

    if (v0) {
        float4* mp = (float4*)(m + (size_t)p0 * 32);
#pragma unroll
        for (int o = 0; o < 8; ++o) mp[o] = acc0[o];
    }
    if (v1) {
        float4* mp = (float4*)(m + (size_t)p1 * 32);
#pragma unroll
        for (int o = 0; o < 8; ++o) mp[o] = acc1[o];
    }
}

// 8 threads/node: hpre[v] = bias + norm(h[v])@root + contiguous CSR message rows
// BN block-partials -> part[] (no atomics)
__global__ __launch_bounds__(256) void k_agg(
    const float* __restrict__ h, const float* __restrict__ m,
    const int* __restrict__ rowptr,
    const float* __restrict__ root, const float* __restrict__ bias,
    const float* __restrict__ stats_prev, const float* __restrict__ gamma,
    const float* __restrict__ beta, int flag,
    float* __restrict__ hpre, float* __restrict__ part)
{
    __shared__ float sc[32], sh[32];
    bn_scsh(stats_prev, gamma, beta, flag, sc, sh);
    __syncthreads();

    int v = blockIdx.x * 32 + (threadIdx.x >> 3);
    int cg = threadIdx.x & 7;
    float4 acc = make_float4(0.f, 0.f, 0.f, 0.f);

    if (v < NN) {
        float hn[32];
        const float4* hp = (const float4*)(h + v * 32);
#pragma unroll
        for (int q = 0; q < 8; ++q) {
            float4 t = hp[q];
            hn[4 * q] = t.x; hn[4 * q + 1] = t.y; hn[4 * q + 2] = t.z; hn[4 * q + 3] = t.w;
        }
        if (flag) {
#pragma unroll
            for (int i = 0; i < 32; ++i) {
                float y = fmaf(hn[i], sc[i], sh[i]);
                hn[i] = y > 0.f ? y : SLOPE * y;
            }
        }
        acc = ((const float4*)bias)[cg];
#pragma unroll
        for (int i = 0; i < 32; ++i) {
            float4 r = ((const float4*)(root + i * 32))[cg];
            acc.x = fmaf(hn[i], r.x, acc.x);
            acc.y = fmaf(hn[i], r.y, acc.y);
            acc.z = fmaf(hn[i], r.z, acc.z);
            acc.w = fmaf(hn[i], r.w, acc.w);
        }
        int q0 = rowptr[v], q1 = rowptr[v + 1];
        for (int p = q0; p < q1; ++p) {
            float4 t = ((const float4*)(m + (size_t)p * 32))[cg];
            acc.x += t.x; acc.y += t.y; acc.z += t.z; acc.w += t.w;
        }
        ((float4*)(hpre + v * 32))[cg] = acc;
    }

    // BN stats: butterfly over 8 nodes/wave, LDS reduce over waves, plain store
    float ss[8] = { acc.x, acc.y, acc.z, acc.w,
                    acc.x * acc.x, acc.y * acc.y, acc.z * acc.z, acc.w * acc.w };
#pragma unroll
    for (int d = 8; d < 64; d <<= 1) {
#pragma unroll
        for (int j = 0; j < 8; ++j) ss[j] += __shfl_xor(ss[j], d);
    }
    __shared__ float ls[2][4][8][4];
    int wave = threadIdx.x >> 6, lane = threadIdx.x & 63;
    if (lane < 8) {
#pragma unroll
        for (int j = 0; j < 4; ++j) {
            ls[0][wave][lane][j] = ss[j];
            ls[1][wave][lane][j] = ss[4 + j];
        }
    }
    __syncthreads();
    if (threadIdx.x < 64) {
        int stat = threadIdx.x >> 5, idx = threadIdx.x & 31;
        int cgg = idx >> 2, ch = idx & 3;
        float val = ls[stat][0][cgg][ch] + ls[stat][1][cgg][ch]
                  + ls[stat][2][cgg][ch] + ls[stat][3][cgg][ch];
        part[blockIdx.x * 64 + threadIdx.x] = val;
    }
}

// reduce block partials -> stats[64]
__global__ __launch_bounds__(256) void k_red(const float* __restrict__ part,
                                             float* __restrict__ stats) {
    __shared__ float buf[256];
    int t = threadIdx.x;
    int idx = t & 63, c = t >> 6;
    float s = 0.f;
    for (int b = c; b < AGG_B; b += 4) s += part[b * 64 + idx];
    buf[t] = s;
    __syncthreads();
    if (t < 64) stats[t] = buf[t] + buf[64 + t] + buf[128 + t] + buf[192 + t];
}

// final-layer norm fused
__global__ __launch_bounds__(256) void k_logits(const float* __restrict__ h,
                                                const float* __restrict__ fcW,
                                                const float* __restrict__ fcb,
                                                const float* __restrict__ stats,
                                                const float* __restrict__ gamma,
                                                const float* __restrict__ beta,
                                                float* __restrict__ out) {
    __shared__ float sc[32], sh[32];
    bn_scsh(stats, gamma, beta, 1, sc, sh);
    __syncthreads();

    int v = blockIdx.x * blockDim.x + threadIdx.x;
    if (v >= NN) return;
    float hv[32];
    const float4* hp = (const float4*)(h + v * 32);
#pragma unroll
    for (int q = 0; q < 8; ++q) {
        float4 t = hp[q];
        hv[4 * q] = t.x; hv[4 * q + 1] = t.y; hv[4 * q + 2] = t.z; hv[4 * q + 3] = t.w;
    }
#pragma unroll
    for (int i = 0; i < 32; ++i) {
        float y = fmaf(hv[i], sc[i], sh[i]);
        hv[i] = y > 0.f ? y : SLOPE * y;
    }
    float lg[13];
#pragma unroll
    for (int c = 0; c < 13; ++c) lg[c] = fcb[c];
#pragma unroll
    for (int i = 0; i < 32; ++i) {
        float z = hv[i];
#pragma unroll
        for (int c = 0; c < 13; ++c) lg[c] = fmaf(z, fcW[i * 13 + c], lg[c]);
    }
    float mx = lg[0];
#pragma unroll
    for (int c = 1; c < 13; ++c) mx = fmaxf(mx, lg[c]);
    float sum = 0.0f;
#pragma unroll
    for (int c = 0; c < 13; ++c) sum += expf(lg[c] - mx);
    float lse = mx + logf(sum);
#pragma unroll
    for (int c = 0; c < 13; ++c) out[v * 13 + c] = lg[c] - lse;
}

// ---------------- launch ----------------
extern "C" void kernel_launch(void* const* d_in, const int* in_sizes, int n_in,
                              void* d_out, int out_size, void* d_ws, size_t ws_size,
                              hipStream_t stream) {
    const float* x     = (const float*)d_in[0];
    const int*   ei    = (const int*)  d_in[1];
    const float* ea    = (const float*)d_in[2];
    const float* netW1 = (const float*)d_in[3];
    const float* netb1 = (const float*)d_in[4];
    const float* netW2 = (const float*)d_in[5];
    const float* netb2 = (const float*)d_in[6];
    const float* root  = (const float*)d_in[7];
    const float* cbias = (const float*)d_in[8];
    const float* gamma = (const float*)d_in[9];
    const float* beta  = (const float*)d_in[10];
    const float* fcW   = (const float*)d_in[11];
    const float* fcb   = (const float*)d_in[12];
    float* out = (float*)d_out;

    char* w = (char*)d_ws;
    float* m      = (float*)(w);                 // 19,200,000 B
    float* hA     = (float*)(w + 19200000);      //  6,400,000 B
    float* hB     = (float*)(w + 25600000);      //  6,400,000 B
    int*   rowptr = (int*)  (w + 32000000);      //    200,064 B
    int*   cursor = (int*)  (w + 32200064);      //    200,064 B
    int*   perm   = (int*)  (w + 32400128);      //    600,000 B
    float* stats  = (float*)(w + 33000128);      //        768 B
    int*   bsum   = (int*)  (w + 33000896);      //      1,024 B
    float* part   = (float*)(w + 33001920);      //    400,128 B
    int*   cnt    = (int*)w;                     // overlaps m (used only before m is written)

    hipMemsetAsync(cnt, 0, (NN + 1) * sizeof(int), stream);

    k_count<<<(EE + 255) / 256, 256, 0, stream>>>(ei, cnt);
    k_scanA<<<SCAN_B, 256, 0, stream>>>(cnt, rowptr, bsum);
    k_scanB<<<1, 256, 0, stream>>>(bsum);
    k_scanC<<<SCAN_B, 256, 0, stream>>>(rowptr, cursor, bsum);
    k_fill <<<(EE + 255) / 256, 256, 0, stream>>>(ei, cursor, perm);

    const float* hcur = x;
    float* bufs[2] = { hA, hB };
    for (int i = 0; i < 3; ++i) {
        float* hnext = bufs[i & 1];
        const float* stprev = stats + (i - 1) * 64;   // unused when i==0
        k_msg<<<(EE + 511) / 512, 256, 0, stream>>>(
            hcur, ei, ea, netW1 + i * 20, netb1 + i * 10,
            netW2 + i * 10240, netb2 + i * 1024,
            stprev, gamma + (i - 1) * 32, beta + (i - 1) * 32, i > 0, perm, m);
        k_agg<<<AGG_B, 256, 0, stream>>>(
            hcur, m, rowptr, root + i * 1024, cbias + i * 32,
            stprev, gamma + (i - 1) * 32, beta + (i - 1) * 32, i > 0,
            hnext, part);
        k_red<<<1, 256, 0, stream>>>(part, stats + i * 64);
        hcur = hnext;
    }
    k_logits<<<(NN + 255) / 256, 256, 0, stream>>>(
        hcur, fcW, fcb, stats + 2 * 64, gamma + 2 * 32, beta + 2 * 32, out);
}

// Round 9
// 424.311 us; speedup vs baseline: 1.8601x; 1.8601x over previous
//
#include <hip/hip_runtime.h>

#define NN 50000
#define EE 150000
#define BN_EPS 1e-5f
#define SLOPE 0.01f
#define SCAN_B 196          // ceil((NN+1)/256)
#define AGG_B  1563         // ceil(NN/32)

// ---------------- CSR build ----------------
__global__ __launch_bounds__(256) void k_count(const int* __restrict__ ei, int* __restrict__ cnt) {
    int e = blockIdx.x * blockDim.x + threadIdx.x;
    if (e < EE) atomicAdd(&cnt[ei[EE + e]], 1);
}

__global__ __launch_bounds__(256) void k_scanA(const int* __restrict__ cnt,
                                               int* __restrict__ rowptr,
                                               int* __restrict__ bsum) {
    __shared__ int buf[256];
    int t = threadIdx.x;
    int idx = blockIdx.x * 256 + t;
    int v = (idx <= NN) ? cnt[idx] : 0;
    buf[t] = v;
    __syncthreads();
    for (int off = 1; off < 256; off <<= 1) {
        int add = (t >= off) ? buf[t - off] : 0;
        __syncthreads();
        buf[t] += add;
        __syncthreads();
    }
    if (idx <= NN) rowptr[idx] = buf[t] - v;
    if (t == 255) bsum[blockIdx.x] = buf[255];
}

__global__ __launch_bounds__(256) void k_scanB(int* __restrict__ bsum) {
    __shared__ int buf[256];
    int t = threadIdx.x;
    int v = (t < SCAN_B) ? bsum[t] : 0;
    buf[t] = v;
    __syncthreads();
    for (int off = 1; off < 256; off <<= 1) {
        int add = (t >= off) ? buf[t - off] : 0;
        __syncthreads();
        buf[t] += add;
        __syncthreads();
    }
    if (t < SCAN_B) bsum[t] = buf[t] - v;
}

__global__ __launch_bounds__(256) void k_scanC(int* __restrict__ rowptr,
                                               int* __restrict__ cursor,
                                               const int* __restrict__ bsum) {
    int idx = blockIdx.x * 256 + threadIdx.x;
    if (idx <= NN) {
        int r = rowptr[idx] + bsum[blockIdx.x];
        rowptr[idx] = r;
        cursor[idx] = r;
    }
}

__global__ __launch_bounds__(256) void k_fill(const int* __restrict__ ei,
                                              int* __restrict__ cursor,
                                              int* __restrict__ perm) {
    int e = blockIdx.x * blockDim.x + threadIdx.x;
    if (e < EE) perm[e] = atomicAdd(&cursor[ei[EE + e]], 1);
}

// in-block BN finalize: stats -> scale/shift in LDS (caller syncs)
__device__ __forceinline__ void bn_scsh(const float* __restrict__ stats,
                                        const float* __restrict__ gamma,
                                        const float* __restrict__ beta,
                                        int flag, float* sc, float* sh) {
    if (flag && threadIdx.x < 32) {
        int o = threadIdx.x;
        float mu = stats[o] * (1.0f / NN);
        float var = stats[32 + o] * (1.0f / NN) - mu * mu;
        float s = gamma[o] * rsqrtf(var + BN_EPS);
        sc[o] = s;
        sh[o] = fmaf(-mu, s, beta[o]);
    }
}

// ---------------- per-layer kernels ----------------
// 2 threads per edge (o-split by 16); two-phase 24.9KB LDS staging (6 blocks/CU);
// h read through fused BN+leakyrelu; ek recomputed per slot (no dynamic reg indexing)
__global__ __launch_bounds__(256) void k_msg(
    const float* __restrict__ h, const int* __restrict__ ei,
    const float* __restrict__ ea, const float* __restrict__ W1,
    const float* __restrict__ b1, const float* __restrict__ W2,
    const float* __restrict__ b2,
    const float* __restrict__ stats, const float* __restrict__ gamma,
    const float* __restrict__ beta, int flag,
    const int* __restrict__ perm, float* __restrict__ m)
{
    __shared__ float4 sw[1536];          // 6 matrices x 256 float4 = 24.6 KB
    __shared__ float sc[32], sh[32];

    int t = threadIdx.x;
    const float4* W2v = (const float4*)W2;
    // phase A stage: W2 k=0..4 into slots 0..4, b2 into slot 5
#pragma unroll
    for (int j = 0; j < 5; ++j) sw[j * 256 + t] = W2v[j * 256 + t];
    sw[5 * 256 + t] = ((const float4*)b2)[t];
    bn_scsh(stats, gamma, beta, flag, sc, sh);
    __syncthreads();

    int tid = blockIdx.x * 256 + t;
    int e = tid >> 1;
    int half = tid & 1;
    bool valid = e < EE;
    int s = valid ? ei[e] : 0;
    float2 a = valid ? ((const float2*)ea)[e] : make_float2(0.f, 0.f);
    int p = valid ? perm[e] : 0;

    float hv[32];
    const float4* hp = (const float4*)(h + s * 32);
#pragma unroll
    for (int q = 0; q < 8; ++q) {
        float4 tt = hp[q];
        hv[4 * q] = tt.x; hv[4 * q + 1] = tt.y; hv[4 * q + 2] = tt.z; hv[4 * q + 3] = tt.w;
    }
    if (flag) {
#pragma unroll
        for (int i = 0; i < 32; ++i) {
            float y = fmaf(hv[i], sc[i], sh[i]);
            hv[i] = y > 0.f ? y : SLOPE * y;
        }
    }

    float4 acc[4];
#pragma unroll
    for (int o = 0; o < 4; ++o) acc[o] = make_float4(0.f, 0.f, 0.f, 0.f);

    // phase A compute: slots 0..4 = ek[0..4], slot 5 = b2 (ekk = 1)
    for (int j = 0; j < 6; ++j) {
        float ekk = (j < 5)
            ? fmaxf(fmaf(a.x, W1[j], fmaf(a.y, W1[10 + j], b1[j])), 0.0f)
            : 1.0f;
        const float4* wk = &sw[j * 256];
#pragma unroll
        for (int i = 0; i < 32; ++i) {
            float z = ekk * hv[i];
            const float4* wr = wk + i * 8 + half * 4;
#pragma unroll
            for (int o = 0; o < 4; ++o) {
                float4 wv = wr[o];
                acc[o].x = fmaf(z, wv.x, acc[o].x);
                acc[o].y = fmaf(z, wv.y, acc[o].y);
                acc[o].z = fmaf(z, wv.z, acc[o].z);
                acc[o].w = fmaf(z, wv.w, acc[o].w);
            }
        }
    }

    __syncthreads();                     // all waves done reading phase-A weights
    // phase B stage: W2 k=5..9 into slots 0..4
#pragma unroll
    for (int j = 0; j < 5; ++j) sw[j * 256 + t] = W2v[(5 + j) * 256 + t];
    __syncthreads();

    for (int j = 0; j < 5; ++j) {
        float ekk = fmaxf(fmaf(a.x, W1[5 + j], fmaf(a.y, W1[15 + j], b1[5 + j])), 0.0f);
        const float4* wk = &sw[j * 256];
#pragma unroll
        for (int i = 0; i < 32; ++i) {
            float z = ekk * hv[i];
            const float4* wr = wk + i * 8 + half * 4;
#pragma unroll
            for (int o = 0; o < 4; ++o) {
                float4 wv = wr[o];
                acc[o].x = fmaf(z, wv.x, acc[o].x);
                acc[o].y = fmaf(z, wv.y, acc[o].y);
                acc[o].z = fmaf(z, wv.z, acc[o].z);
                acc[o].w = fmaf(z, wv.w, acc[o].w);
            }
        }
    }

    if (valid) {
        float4* mp = (float4*)(m + (size_t)p * 32 + half * 16);
#pragma unroll
        for (int o = 0; o < 4; ++o) mp[o] = acc[o];
    }
}

// 8 threads/node: hpre[v] = bias + norm(h[v])@root + contiguous CSR message rows
// degree loop unrolled x2 for memory-level parallelism; BN stats via 64 atomics/block
__global__ __launch_bounds__(256) void k_agg(
    const float* __restrict__ h, const float* __restrict__ m,
    const int* __restrict__ rowptr,
    const float* __restrict__ root, const float* __restrict__ bias,
    const float* __restrict__ stats_prev, const float* __restrict__ gamma,
    const float* __restrict__ beta, int flag,
    float* __restrict__ hpre, float* __restrict__ stats_out)
{
    __shared__ float sc[32], sh[32];
    bn_scsh(stats_prev, gamma, beta, flag, sc, sh);
    __syncthreads();

    int v = blockIdx.x * 32 + (threadIdx.x >> 3);
    int cg = threadIdx.x & 7;
    float4 acc = make_float4(0.f, 0.f, 0.f, 0.f);

    if (v < NN) {
        float hn[32];
        const float4* hp = (const float4*)(h + v * 32);
#pragma unroll
        for (int q = 0; q < 8; ++q) {
            float4 t = hp[q];
            hn[4 * q] = t.x; hn[4 * q + 1] = t.y; hn[4 * q + 2] = t.z; hn[4 * q + 3] = t.w;
        }
        if (flag) {
#pragma unroll
            for (int i = 0; i < 32; ++i) {
                float y = fmaf(hn[i], sc[i], sh[i]);
                hn[i] = y > 0.f ? y : SLOPE * y;
            }
        }
        acc = ((const float4*)bias)[cg];
#pragma unroll
        for (int i = 0; i < 32; ++i) {
            float4 r = ((const float4*)(root + i * 32))[cg];
            acc.x = fmaf(hn[i], r.x, acc.x);
            acc.y = fmaf(hn[i], r.y, acc.y);
            acc.z = fmaf(hn[i], r.z, acc.z);
            acc.w = fmaf(hn[i], r.w, acc.w);
        }
        int q0 = rowptr[v], q1 = rowptr[v + 1];
        float4 acc2 = make_float4(0.f, 0.f, 0.f, 0.f);
        int p = q0;
        for (; p + 1 < q1; p += 2) {                      // 2 independent loads in flight
            float4 t0 = ((const float4*)(m + (size_t)p * 32))[cg];
            float4 t1 = ((const float4*)(m + (size_t)(p + 1) * 32))[cg];
            acc.x += t0.x; acc.y += t0.y; acc.z += t0.z; acc.w += t0.w;
            acc2.x += t1.x; acc2.y += t1.y; acc2.z += t1.z; acc2.w += t1.w;
        }
        if (p < q1) {
            float4 t0 = ((const float4*)(m + (size_t)p * 32))[cg];
            acc.x += t0.x; acc.y += t0.y; acc.z += t0.z; acc.w += t0.w;
        }
        acc.x += acc2.x; acc.y += acc2.y; acc.z += acc2.z; acc.w += acc2.w;
        ((float4*)(hpre + v * 32))[cg] = acc;
    }

    // BN stats: butterfly over 8 nodes/wave, LDS reduce over waves, 64 atomics/block
    float ss[8] = { acc.x, acc.y, acc.z, acc.w,
                    acc.x * acc.x, acc.y * acc.y, acc.z * acc.z, acc.w * acc.w };
#pragma unroll
    for (int d = 8; d < 64; d <<= 1) {
#pragma unroll
        for (int j = 0; j < 8; ++j) ss[j] += __shfl_xor(ss[j], d);
    }
    __shared__ float ls[2][4][8][4];
    int wave = threadIdx.x >> 6, lane = threadIdx.x & 63;
    if (lane < 8) {
#pragma unroll
        for (int j = 0; j < 4; ++j) {
            ls[0][wave][lane][j] = ss[j];
            ls[1][wave][lane][j] = ss[4 + j];
        }
    }
    __syncthreads();
    if (threadIdx.x < 64) {
        int stat = threadIdx.x >> 5, idx = threadIdx.x & 31;
        int cgg = idx >> 2, ch = idx & 3;
        float val = ls[stat][0][cgg][ch] + ls[stat][1][cgg][ch]
                  + ls[stat][2][cgg][ch] + ls[stat][3][cgg][ch];
        unsafeAtomicAdd(&stats_out[stat * 32 + idx], val);
    }
}

// final-layer norm fused
__global__ __launch_bounds__(256) void k_logits(const float* __restrict__ h,
                                                const float* __restrict__ fcW,
                                                const float* __restrict__ fcb,
                                                const float* __restrict__ stats,
                                                const float* __restrict__ gamma,
                                                const float* __restrict__ beta,
                                                float* __restrict__ out) {
    __shared__ float sc[32], sh[32];
    bn_scsh(stats, gamma, beta, 1, sc, sh);
    __syncthreads();

    int v = blockIdx.x * blockDim.x + threadIdx.x;
    if (v >= NN) return;
    float hv[32];
    const float4* hp = (const float4*)(h + v * 32);
#pragma unroll
    for (int q = 0; q < 8; ++q) {
        float4 t = hp[q];
        hv[4 * q] = t.x; hv[4 * q + 1] = t.y; hv[4 * q + 2] = t.z; hv[4 * q + 3] = t.w;
    }
#pragma unroll
    for (int i = 0; i < 32; ++i) {
        float y = fmaf(hv[i], sc[i], sh[i]);
        hv[i] = y > 0.f ? y : SLOPE * y;
    }
    float lg[13];
#pragma unroll
    for (int c = 0; c < 13; ++c) lg[c] = fcb[c];
#pragma unroll
    for (int i = 0; i < 32; ++i) {
        float z = hv[i];
#pragma unroll
        for (int c = 0; c < 13; ++c) lg[c] = fmaf(z, fcW[i * 13 + c], lg[c]);
    }
    float mx = lg[0];
#pragma unroll
    for (int c = 1; c < 13; ++c) mx = fmaxf(mx, lg[c]);
    float sum = 0.0f;
#pragma unroll
    for (int c = 0; c < 13; ++c) sum += expf(lg[c] - mx);
    float lse = mx + logf(sum);
#pragma unroll
    for (int c = 0; c < 13; ++c) out[v * 13 + c] = lg[c] - lse;
}

// ---------------- launch ----------------
extern "C" void kernel_launch(void* const* d_in, const int* in_sizes, int n_in,
                              void* d_out, int out_size, void* d_ws, size_t ws_size,
                              hipStream_t stream) {
    const float* x     = (const float*)d_in[0];
    const int*   ei    = (const int*)  d_in[1];
    const float* ea    = (const float*)d_in[2];
    const float* netW1 = (const float*)d_in[3];
    const float* netb1 = (const float*)d_in[4];
    const float* netW2 = (const float*)d_in[5];
    const float* netb2 = (const float*)d_in[6];
    const float* root  = (const float*)d_in[7];
    const float* cbias = (const float*)d_in[8];
    const float* gamma = (const float*)d_in[9];
    const float* beta  = (const float*)d_in[10];
    const float* fcW   = (const float*)d_in[11];
    const float* fcb   = (const float*)d_in[12];
    float* out = (float*)d_out;

    char* w = (char*)d_ws;
    float* m      = (float*)(w);                 // 19,200,000 B
    float* hA     = (float*)(w + 19200000);      //  6,400,000 B
    float* hB     = (float*)(w + 25600000);      //  6,400,000 B
    int*   rowptr = (int*)  (w + 32000000);      //    200,064 B
    int*   cursor = (int*)  (w + 32200064);      //    200,064 B
    int*   perm   = (int*)  (w + 32400128);      //    600,000 B
    float* stats  = (float*)(w + 33000128);      //        768 B
    int*   bsum   = (int*)  (w + 33000896);      //      1,024 B
    int*   cnt    = (int*)w;                     // overlaps m (used only before m is written)

    hipMemsetAsync(cnt, 0, (NN + 1) * sizeof(int), stream);
    hipMemsetAsync(stats, 0, 768, stream);

    k_count<<<(EE + 255) / 256, 256, 0, stream>>>(ei, cnt);
    k_scanA<<<SCAN_B, 256, 0, stream>>>(cnt, rowptr, bsum);
    k_scanB<<<1, 256, 0, stream>>>(bsum);
    k_scanC<<<SCAN_B, 256, 0, stream>>>(rowptr, cursor, bsum);
    k_fill <<<(EE + 255) / 256, 256, 0, stream>>>(ei, cursor, perm);

    const float* hcur = x;
    float* bufs[2] = { hA, hB };
    for (int i = 0; i < 3; ++i) {
        float* hnext = bufs[i & 1];
        const float* stprev = stats + (i - 1) * 64;   // unused when i==0
        k_msg<<<(2 * EE + 255) / 256, 256, 0, stream>>>(
            hcur, ei, ea, netW1 + i * 20, netb1 + i * 10,
            netW2 + i * 10240, netb2 + i * 1024,
            stprev, gamma + (i - 1) * 32, beta + (i - 1) * 32, i > 0, perm, m);
        k_agg<<<AGG_B, 256, 0, stream>>>(
            hcur, m, rowptr, root + i * 1024, cbias + i * 32,
            stprev, gamma + (i - 1) * 32, beta + (i - 1) * 32, i > 0,
            hnext, stats + i * 64);
        hcur = hnext;
    }
    k_logits<<<(NN + 255) / 256, 256, 0, stream>>>(
        hcur, fcW, fcb, stats + 2 * 64, gamma + 2 * 32, beta + 2 * 32, out);
}

// Round 10
// 312.317 us; speedup vs baseline: 2.5271x; 1.3586x over previous
//
#include <hip/hip_runtime.h>

#define NN 50000
#define EE 150000
#define BN_EPS 1e-5f
#define SLOPE 0.01f
#define SCAN_B 196          // ceil((NN+1)/256)
#define AGG_B  1563         // ceil(NN/32)
#define MSG_B  2344         // ceil(EE/64)

typedef __attribute__((ext_vector_type(8))) short bf16x8;
typedef __attribute__((ext_vector_type(4))) float f32x4;

// ---------------- CSR build ----------------
__global__ __launch_bounds__(256) void k_count(const int* __restrict__ ei, int* __restrict__ cnt) {
    int e = blockIdx.x * blockDim.x + threadIdx.x;
    if (e < EE) atomicAdd(&cnt[ei[EE + e]], 1);
}

__global__ __launch_bounds__(256) void k_scanA(const int* __restrict__ cnt,
                                               int* __restrict__ rowptr,
                                               int* __restrict__ bsum) {
    __shared__ int buf[256];
    int t = threadIdx.x;
    int idx = blockIdx.x * 256 + t;
    int v = (idx <= NN) ? cnt[idx] : 0;
    buf[t] = v;
    __syncthreads();
    for (int off = 1; off < 256; off <<= 1) {
        int add = (t >= off) ? buf[t - off] : 0;
        __syncthreads();
        buf[t] += add;
        __syncthreads();
    }
    if (idx <= NN) rowptr[idx] = buf[t] - v;
    if (t == 255) bsum[blockIdx.x] = buf[255];
}

__global__ __launch_bounds__(256) void k_scanB(int* __restrict__ bsum) {
    __shared__ int buf[256];
    int t = threadIdx.x;
    int v = (t < SCAN_B) ? bsum[t] : 0;
    buf[t] = v;
    __syncthreads();
    for (int off = 1; off < 256; off <<= 1) {
        int add = (t >= off) ? buf[t - off] : 0;
        __syncthreads();
        buf[t] += add;
        __syncthreads();
    }
    if (t < SCAN_B) bsum[t] = buf[t] - v;
}

__global__ __launch_bounds__(256) void k_scanC(int* __restrict__ rowptr,
                                               int* __restrict__ cursor,
                                               const int* __restrict__ bsum) {
    int idx = blockIdx.x * 256 + threadIdx.x;
    if (idx <= NN) {
        int r = rowptr[idx] + bsum[blockIdx.x];
        rowptr[idx] = r;
        cursor[idx] = r;
    }
}

__global__ __launch_bounds__(256) void k_fill(const int* __restrict__ ei,
                                              int* __restrict__ cursor,
                                              int* __restrict__ perm) {
    int e = blockIdx.x * blockDim.x + threadIdx.x;
    if (e < EE) perm[e] = atomicAdd(&cursor[ei[EE + e]], 1);
}

// in-block BN finalize: stats -> scale/shift in LDS (caller syncs)
__device__ __forceinline__ void bn_scsh(const float* __restrict__ stats,
                                        const float* __restrict__ gamma,
                                        const float* __restrict__ beta,
                                        int flag, float* sc, float* sh) {
    if (flag && threadIdx.x < 32) {
        int o = threadIdx.x;
        float mu = stats[o] * (1.0f / NN);
        float var = stats[32 + o] * (1.0f / NN) - mu * mu;
        float s = gamma[o] * rsqrtf(var + BN_EPS);
        sc[o] = s;
        sh[o] = fmaf(-mu, s, beta[o]);
    }
}

// ---------------- per-layer kernels ----------------
// MFMA message kernel: m = u @ Wf, u[e,(k,i)] = ek[e,k]*hn[e,i]  (E x 352 @ 352 x 32)
// 64 edges/block, 4 waves x 16 edges, 11 K-steps x 2 output tiles of mfma_f32_16x16x32_bf16.
// Wf^T staged in LDS pre-swizzled to exact A-fragment order (lane-linear ds_read_b128).
__global__ __launch_bounds__(256) void k_msg(
    const float* __restrict__ h, const int* __restrict__ ei,
    const float* __restrict__ ea, const float* __restrict__ W1,
    const float* __restrict__ b1, const float* __restrict__ W2,
    const float* __restrict__ b2,
    const float* __restrict__ stats, const float* __restrict__ gamma,
    const float* __restrict__ beta, int flag,
    const int* __restrict__ perm, float* __restrict__ m)
{
    __shared__ unsigned sWu[5632];   // 22 frags x 1024 B: bf16 Wf^T in A-frag order
    __shared__ float hnF[2048];      // 4 waves x 2 halves x 64 lanes x 4 f32 (B source)
    __shared__ float ekL[768];       // ek[64][12]
    __shared__ float sc[32], sh[32];

    int t = threadIdx.x;
    bn_scsh(stats, gamma, beta, flag, sc, sh);
    __syncthreads();                 // sc/sh ready for hn staging

    // ---- stage Wf^T (W2 k=0..9 + b2 as slot 10) in fragment order, bf16-truncated ----
#pragma unroll
    for (int it = 0; it < 22; ++it) {
        int idx = t + 256 * it;          // u32 index, 5632 total
        int frag = idx >> 8;             // k-step*2 + tile
        int rem  = idx & 255;
        int lane = rem >> 2;
        int j0   = (rem & 3) * 2;
        int tile = frag & 1;
        int kstep = frag >> 1;
        int o  = tile * 16 + (lane & 15);
        int kk = kstep * 32 + (lane >> 4) * 8 + j0;
        float v0, v1;
        if (kk < 320) {
            int base = (kk >> 5) * 1024 + (kk & 31) * 32 + o;
            v0 = W2[base];
            v1 = W2[base + 32];
        } else {
            int base = (kk - 320) * 32 + o;
            v0 = b2[base];
            v1 = b2[base + 32];
        }
        sWu[idx] = __builtin_amdgcn_perm(__float_as_uint(v1), __float_as_uint(v0), 0x07060302u);
    }

    // ---- stage ek and hn (BN+leakyrelu applied) ----
    int e_loc = t & 63;
    int c     = t >> 6;
    int e_g   = blockIdx.x * 64 + e_loc;
    bool ev   = e_g < EE;

    if (c == 0) {
        float2 a = ev ? ((const float2*)ea)[e_g] : make_float2(0.f, 0.f);
#pragma unroll
        for (int k = 0; k < 10; ++k)
            ekL[e_loc * 12 + k] = fmaxf(fmaf(a.x, W1[k], fmaf(a.y, W1[10 + k], b1[k])), 0.0f);
        ekL[e_loc * 12 + 10] = 1.0f;
    }

    {
        float4 f0 = make_float4(0.f, 0.f, 0.f, 0.f);
        float4 f1 = make_float4(0.f, 0.f, 0.f, 0.f);
        if (ev) {
            int s = ei[e_g];
            f0 = *(const float4*)(h + s * 32 + c * 8);
            f1 = *(const float4*)(h + s * 32 + c * 8 + 4);
            if (flag) {
                int i0 = c * 8;
                f0.x = fmaf(f0.x, sc[i0+0], sh[i0+0]); f0.x = f0.x > 0.f ? f0.x : SLOPE*f0.x;
                f0.y = fmaf(f0.y, sc[i0+1], sh[i0+1]); f0.y = f0.y > 0.f ? f0.y : SLOPE*f0.y;
                f0.z = fmaf(f0.z, sc[i0+2], sh[i0+2]); f0.z = f0.z > 0.f ? f0.z : SLOPE*f0.z;
                f0.w = fmaf(f0.w, sc[i0+3], sh[i0+3]); f0.w = f0.w > 0.f ? f0.w : SLOPE*f0.w;
                f1.x = fmaf(f1.x, sc[i0+4], sh[i0+4]); f1.x = f1.x > 0.f ? f1.x : SLOPE*f1.x;
                f1.y = fmaf(f1.y, sc[i0+5], sh[i0+5]); f1.y = f1.y > 0.f ? f1.y : SLOPE*f1.y;
                f1.z = fmaf(f1.z, sc[i0+6], sh[i0+6]); f1.z = f1.z > 0.f ? f1.z : SLOPE*f1.z;
                f1.w = fmaf(f1.w, sc[i0+7], sh[i0+7]); f1.w = f1.w > 0.f ? f1.w : SLOPE*f1.w;
            }
        }
        int w = e_loc >> 4;
        int l = (e_loc & 15) + c * 16;   // reader lane that consumes this chunk
        *(float4*)&hnF[w * 512 + l * 4]       = f0;
        *(float4*)&hnF[w * 512 + 256 + l * 4] = f1;
    }
    __syncthreads();

    // ---- MFMA main loop ----
    int lane = t & 63;
    int w    = t >> 6;
    int el   = w * 16 + (lane & 15);     // this lane's edge (B col = lane&15)
    f32x4 h0 = *(const f32x4*)&hnF[w * 512 + lane * 4];
    f32x4 h1 = *(const f32x4*)&hnF[w * 512 + 256 + lane * 4];
    float ekv[11];
#pragma unroll
    for (int k = 0; k < 11; ++k) ekv[k] = ekL[el * 12 + k];

    f32x4 acc0 = {0.f, 0.f, 0.f, 0.f};
    f32x4 acc1 = {0.f, 0.f, 0.f, 0.f};
#pragma unroll
    for (int k = 0; k < 11; ++k) {
        float ekk = ekv[k];
        union { unsigned u[4]; bf16x8 v; } B;
        B.u[0] = __builtin_amdgcn_perm(__float_as_uint(ekk * h0.y), __float_as_uint(ekk * h0.x), 0x07060302u);
        B.u[1] = __builtin_amdgcn_perm(__float_as_uint(ekk * h0.w), __float_as_uint(ekk * h0.z), 0x07060302u);
        B.u[2] = __builtin_amdgcn_perm(__float_as_uint(ekk * h1.y), __float_as_uint(ekk * h1.x), 0x07060302u);
        B.u[3] = __builtin_amdgcn_perm(__float_as_uint(ekk * h1.w), __float_as_uint(ekk * h1.z), 0x07060302u);
        bf16x8 A0 = *(const bf16x8*)&sWu[(k * 2)     * 256 + lane * 4];
        bf16x8 A1 = *(const bf16x8*)&sWu[(k * 2 + 1) * 256 + lane * 4];
        acc0 = __builtin_amdgcn_mfma_f32_16x16x32_bf16(A0, B.v, acc0, 0, 0, 0);
        acc1 = __builtin_amdgcn_mfma_f32_16x16x32_bf16(A1, B.v, acc1, 0, 0, 0);
    }

    // C layout: col = lane&15 = edge, row = (lane>>4)*4 + reg = output -> float4 per lane
    if (e_g - e_loc + el < EE) {
        int p = perm[blockIdx.x * 64 + el];
        int r = (lane >> 4) * 4;
        *(f32x4*)(m + (size_t)p * 32 + r)      = acc0;
        *(f32x4*)(m + (size_t)p * 32 + 16 + r) = acc1;
    }
}

// 8 threads/node: hpre[v] = bias + norm(h[v])@root + contiguous CSR message rows
__global__ __launch_bounds__(256) void k_agg(
    const float* __restrict__ h, const float* __restrict__ m,
    const int* __restrict__ rowptr,
    const float* __restrict__ root, const float* __restrict__ bias,
    const float* __restrict__ stats_prev, const float* __restrict__ gamma,
    const float* __restrict__ beta, int flag,
    float* __restrict__ hpre, float* __restrict__ stats_out)
{
    __shared__ float sc[32], sh[32];
    bn_scsh(stats_prev, gamma, beta, flag, sc, sh);
    __syncthreads();

    int v = blockIdx.x * 32 + (threadIdx.x >> 3);
    int cg = threadIdx.x & 7;
    float4 acc = make_float4(0.f, 0.f, 0.f, 0.f);

    if (v < NN) {
        float hn[32];
        const float4* hp = (const float4*)(h + v * 32);
#pragma unroll
        for (int q = 0; q < 8; ++q) {
            float4 t = hp[q];
            hn[4 * q] = t.x; hn[4 * q + 1] = t.y; hn[4 * q + 2] = t.z; hn[4 * q + 3] = t.w;
        }
        if (flag) {
#pragma unroll
            for (int i = 0; i < 32; ++i) {
                float y = fmaf(hn[i], sc[i], sh[i]);
                hn[i] = y > 0.f ? y : SLOPE * y;
            }
        }
        acc = ((const float4*)bias)[cg];
#pragma unroll
        for (int i = 0; i < 32; ++i) {
            float4 r = ((const float4*)(root + i * 32))[cg];
            acc.x = fmaf(hn[i], r.x, acc.x);
            acc.y = fmaf(hn[i], r.y, acc.y);
            acc.z = fmaf(hn[i], r.z, acc.z);
            acc.w = fmaf(hn[i], r.w, acc.w);
        }
        int q0 = rowptr[v], q1 = rowptr[v + 1];
        float4 acc2 = make_float4(0.f, 0.f, 0.f, 0.f);
        int p = q0;
        for (; p + 1 < q1; p += 2) {
            float4 t0 = ((const float4*)(m + (size_t)p * 32))[cg];
            float4 t1 = ((const float4*)(m + (size_t)(p + 1) * 32))[cg];
            acc.x += t0.x; acc.y += t0.y; acc.z += t0.z; acc.w += t0.w;
            acc2.x += t1.x; acc2.y += t1.y; acc2.z += t1.z; acc2.w += t1.w;
        }
        if (p < q1) {
            float4 t0 = ((const float4*)(m + (size_t)p * 32))[cg];
            acc.x += t0.x; acc.y += t0.y; acc.z += t0.z; acc.w += t0.w;
        }
        acc.x += acc2.x; acc.y += acc2.y; acc.z += acc2.z; acc.w += acc2.w;
        ((float4*)(hpre + v * 32))[cg] = acc;
    }

    float ss[8] = { acc.x, acc.y, acc.z, acc.w,
                    acc.x * acc.x, acc.y * acc.y, acc.z * acc.z, acc.w * acc.w };
#pragma unroll
    for (int d = 8; d < 64; d <<= 1) {
#pragma unroll
        for (int j = 0; j < 8; ++j) ss[j] += __shfl_xor(ss[j], d);
    }
    __shared__ float ls[2][4][8][4];
    int wave = threadIdx.x >> 6, lane = threadIdx.x & 63;
    if (lane < 8) {
#pragma unroll
        for (int j = 0; j < 4; ++j) {
            ls[0][wave][lane][j] = ss[j];
            ls[1][wave][lane][j] = ss[4 + j];
        }
    }
    __syncthreads();
    if (threadIdx.x < 64) {
        int stat = threadIdx.x >> 5, idx = threadIdx.x & 31;
        int cgg = idx >> 2, ch = idx & 3;
        float val = ls[stat][0][cgg][ch] + ls[stat][1][cgg][ch]
                  + ls[stat][2][cgg][ch] + ls[stat][3][cgg][ch];
        unsafeAtomicAdd(&stats_out[stat * 32 + idx], val);
    }
}

// final-layer norm fused
__global__ __launch_bounds__(256) void k_logits(const float* __restrict__ h,
                                                const float* __restrict__ fcW,
                                                const float* __restrict__ fcb,
                                                const float* __restrict__ stats,
                                                const float* __restrict__ gamma,
                                                const float* __restrict__ beta,
                                                float* __restrict__ out) {
    __shared__ float sc[32], sh[32];
    bn_scsh(stats, gamma, beta, 1, sc, sh);
    __syncthreads();

    int v = blockIdx.x * blockDim.x + threadIdx.x;
    if (v >= NN) return;
    float hv[32];
    const float4* hp = (const float4*)(h + v * 32);
#pragma unroll
    for (int q = 0; q < 8; ++q) {
        float4 t = hp[q];
        hv[4 * q] = t.x; hv[4 * q + 1] = t.y; hv[4 * q + 2] = t.z; hv[4 * q + 3] = t.w;
    }
#pragma unroll
    for (int i = 0; i < 32; ++i) {
        float y = fmaf(hv[i], sc[i], sh[i]);
        hv[i] = y > 0.f ? y : SLOPE * y;
    }
    float lg[13];
#pragma unroll
    for (int c = 0; c < 13; ++c) lg[c] = fcb[c];
#pragma unroll
    for (int i = 0; i < 32; ++i) {
        float z = hv[i];
#pragma unroll
        for (int c = 0; c < 13; ++c) lg[c] = fmaf(z, fcW[i * 13 + c], lg[c]);
    }
    float mx = lg[0];
#pragma unroll
    for (int c = 1; c < 13; ++c) mx = fmaxf(mx, lg[c]);
    float sum = 0.0f;
#pragma unroll
    for (int c = 0; c < 13; ++c) sum += expf(lg[c] - mx);
    float lse = mx + logf(sum);
#pragma unroll
    for (int c = 0; c < 13; ++c) out[v * 13 + c] = lg[c] - lse;
}

// ---------------- launch ----------------
extern "C" void kernel_launch(void* const* d_in, const int* in_sizes, int n_in,
                              void* d_out, int out_size, void* d_ws, size_t ws_size,
                              hipStream_t stream) {
    const float* x     = (const float*)d_in[0];
    const int*   ei    = (const int*)  d_in[1];
    const float* ea    = (const float*)d_in[2];
    const float* netW1 = (const float*)d_in[3];
    const float* netb1 = (const float*)d_in[4];
    const float* netW2 = (const float*)d_in[5];
    const float* netb2 = (const float*)d_in[6];
    const float* root  = (const float*)d_in[7];
    const float* cbias = (const float*)d_in[8];
    const float* gamma = (const float*)d_in[9];
    const float* beta  = (const float*)d_in[10];
    const float* fcW   = (const float*)d_in[11];
    const float* fcb   = (const float*)d_in[12];
    float* out = (float*)d_out;

    char* w = (char*)d_ws;
    float* m      = (float*)(w);                 // 19,200,000 B
    float* hA     = (float*)(w + 19200000);      //  6,400,000 B
    float* hB     = (float*)(w + 25600000);      //  6,400,000 B
    int*   rowptr = (int*)  (w + 32000000);      //    200,064 B
    int*   cursor = (int*)  (w + 32200064);      //    200,064 B
    int*   perm   = (int*)  (w + 32400128);      //    600,000 B
    float* stats  = (float*)(w + 33000128);      //        768 B
    int*   bsum   = (int*)  (w + 33000896);      //      1,024 B
    int*   cnt    = (int*)w;                     // overlaps m (used only before m is written)

    hipMemsetAsync(cnt, 0, (NN + 1) * sizeof(int), stream);
    hipMemsetAsync(stats, 0, 768, stream);

    k_count<<<(EE + 255) / 256, 256, 0, stream>>>(ei, cnt);
    k_scanA<<<SCAN_B, 256, 0, stream>>>(cnt, rowptr, bsum);
    k_scanB<<<1, 256, 0, stream>>>(bsum);
    k_scanC<<<SCAN_B, 256, 0, stream>>>(rowptr, cursor, bsum);
    k_fill <<<(EE + 255) / 256, 256, 0, stream>>>(ei, cursor, perm);

    const float* hcur = x;
    float* bufs[2] = { hA, hB };
    for (int i = 0; i < 3; ++i) {
        float* hnext = bufs[i & 1];
        const float* stprev = stats + (i - 1) * 64;   // unused when i==0
        k_msg<<<MSG_B, 256, 0, stream>>>(
            hcur, ei, ea, netW1 + i * 20, netb1 + i * 10,
            netW2 + i * 10240, netb2 + i * 1024,
            stprev, gamma + (i - 1) * 32, beta + (i - 1) * 32, i > 0, perm, m);
        k_agg<<<AGG_B, 256, 0, stream>>>(
            hcur, m, rowptr, root + i * 1024, cbias + i * 32,
            stprev, gamma + (i - 1) * 32, beta + (i - 1) * 32, i > 0,
            hnext, stats + i * 64);
        hcur = hnext;
    }
    k_logits<<<(NN + 255) / 256, 256, 0, stream>>>(
        hcur, fcW, fcb, stats + 2 * 64, gamma + 2 * 32, beta + 2 * 32, out);
}

// Round 11
// 260.310 us; speedup vs baseline: 3.0320x; 1.1998x over previous
//
#include <hip/hip_runtime.h>

#define NN 50000
#define EE 150000
#define BN_EPS 1e-5f
#define SLOPE 0.01f
#define SCAN_B 196          // ceil((NN+1)/256)
#define AGG_B  782          // ceil(NN/64)
#define MSG_B  2344         // ceil(EE/64)

typedef __attribute__((ext_vector_type(8))) short bf16x8;
typedef __attribute__((ext_vector_type(4))) float f32x4;

// ---------------- CSR build ----------------
__global__ __launch_bounds__(256) void k_count(const int* __restrict__ ei, int* __restrict__ cnt) {
    int e = blockIdx.x * blockDim.x + threadIdx.x;
    if (e < EE) atomicAdd(&cnt[ei[EE + e]], 1);
}

__global__ __launch_bounds__(256) void k_scanA(const int* __restrict__ cnt,
                                               int* __restrict__ rowptr,
                                               int* __restrict__ bsum) {
    __shared__ int buf[256];
    int t = threadIdx.x;
    int idx = blockIdx.x * 256 + t;
    int v = (idx <= NN) ? cnt[idx] : 0;
    buf[t] = v;
    __syncthreads();
    for (int off = 1; off < 256; off <<= 1) {
        int add = (t >= off) ? buf[t - off] : 0;
        __syncthreads();
        buf[t] += add;
        __syncthreads();
    }
    if (idx <= NN) rowptr[idx] = buf[t] - v;
    if (t == 255) bsum[blockIdx.x] = buf[255];
}

__global__ __launch_bounds__(256) void k_scanB(int* __restrict__ bsum) {
    __shared__ int buf[256];
    int t = threadIdx.x;
    int v = (t < SCAN_B) ? bsum[t] : 0;
    buf[t] = v;
    __syncthreads();
    for (int off = 1; off < 256; off <<= 1) {
        int add = (t >= off) ? buf[t - off] : 0;
        __syncthreads();
        buf[t] += add;
        __syncthreads();
    }
    if (t < SCAN_B) bsum[t] = buf[t] - v;
}

__global__ __launch_bounds__(256) void k_scanC(int* __restrict__ rowptr,
                                               int* __restrict__ cursor,
                                               const int* __restrict__ bsum) {
    int idx = blockIdx.x * 256 + threadIdx.x;
    if (idx <= NN) {
        int r = rowptr[idx] + bsum[blockIdx.x];
        rowptr[idx] = r;
        cursor[idx] = r;
    }
}

__global__ __launch_bounds__(256) void k_fill(const int* __restrict__ ei,
                                              int* __restrict__ cursor,
                                              int* __restrict__ perm) {
    int e = blockIdx.x * blockDim.x + threadIdx.x;
    if (e < EE) perm[e] = atomicAdd(&cursor[ei[EE + e]], 1);
}

// pre-swizzle Wf = [W2 k=0..9 ; b2] into bf16 A-fragment order (same math as round-10 LDS stage)
__global__ __launch_bounds__(256) void k_wprep(const float* __restrict__ netW2,
                                               const float* __restrict__ netb2,
                                               unsigned* __restrict__ Wfz) {
    int layer = blockIdx.y;
    int idx = blockIdx.x * 256 + threadIdx.x;      // < 5632
    if (idx >= 5632) return;
    const float* W2 = netW2 + layer * 10240;
    const float* b2 = netb2 + layer * 1024;
    int frag = idx >> 8;
    int rem  = idx & 255;
    int lane = rem >> 2;
    int j0   = (rem & 3) * 2;
    int tile = frag & 1;
    int kstep = frag >> 1;
    int o  = tile * 16 + (lane & 15);
    int kk = kstep * 32 + (lane >> 4) * 8 + j0;
    float v0, v1;
    if (kk < 320) {
        int base = (kk >> 5) * 1024 + (kk & 31) * 32 + o;
        v0 = W2[base];
        v1 = W2[base + 32];
    } else {
        int base = (kk - 320) * 32 + o;
        v0 = b2[base];
        v1 = b2[base + 32];
    }
    Wfz[layer * 5632 + idx] =
        __builtin_amdgcn_perm(__float_as_uint(v1), __float_as_uint(v0), 0x07060302u);
}

// in-block BN finalize: stats -> scale/shift in LDS (caller syncs)
__device__ __forceinline__ void bn_scsh(const float* __restrict__ stats,
                                        const float* __restrict__ gamma,
                                        const float* __restrict__ beta,
                                        int flag, float* sc, float* sh) {
    if (flag && threadIdx.x < 32) {
        int o = threadIdx.x;
        float mu = stats[o] * (1.0f / NN);
        float var = stats[32 + o] * (1.0f / NN) - mu * mu;
        float s = gamma[o] * rsqrtf(var + BN_EPS);
        sc[o] = s;
        sh[o] = fmaf(-mu, s, beta[o]);
    }
}

// ---------------- per-layer kernels ----------------
// LDS-free, barrier-free MFMA message kernel. 64 edges/block, 4 waves x 16 edges.
// A-frags read directly from pre-swizzled global Wfz (L1-hot); B built per-lane from h gather.
__global__ __launch_bounds__(256) void k_msg(
    const float* __restrict__ h, const int* __restrict__ ei,
    const float* __restrict__ ea, const float* __restrict__ W1,
    const float* __restrict__ b1, const unsigned* __restrict__ Wfz,
    const float* __restrict__ stats, const float* __restrict__ gamma,
    const float* __restrict__ beta, int flag,
    const int* __restrict__ perm, float* __restrict__ m)
{
    int t = threadIdx.x;
    int lane = t & 63;
    int w = t >> 6;
    int col = lane & 15;
    int chunk = lane >> 4;                 // B-frag k-chunk: k = chunk*8 + j
    int e = blockIdx.x * 64 + w * 16 + col;
    bool ev = e < EE;
    int s = ev ? ei[e] : 0;
    float2 a = ev ? ((const float2*)ea)[e] : make_float2(0.f, 0.f);

    float hv[8];
    *(float4*)&hv[0] = *(const float4*)(h + s * 32 + chunk * 8);
    *(float4*)&hv[4] = *(const float4*)(h + s * 32 + chunk * 8 + 4);

    if (flag) {
        int i0 = chunk * 8;
#pragma unroll
        for (int j = 0; j < 8; ++j) {
            int ch = i0 + j;
            float mu = stats[ch] * (1.0f / NN);
            float var = stats[32 + ch] * (1.0f / NN) - mu * mu;
            float scv = gamma[ch] * rsqrtf(var + BN_EPS);
            float shv = fmaf(-mu, scv, beta[ch]);
            float y = fmaf(hv[j], scv, shv);
            hv[j] = y > 0.f ? y : SLOPE * y;
        }
    }

    float ekv[11];
#pragma unroll
    for (int k = 0; k < 10; ++k)
        ekv[k] = fmaxf(fmaf(a.x, W1[k], fmaf(a.y, W1[10 + k], b1[k])), 0.0f);
    ekv[10] = 1.0f;

    f32x4 acc0 = {0.f, 0.f, 0.f, 0.f};
    f32x4 acc1 = {0.f, 0.f, 0.f, 0.f};
#pragma unroll
    for (int k = 0; k < 11; ++k) {
        float ekk = ekv[k];
        union { unsigned u[4]; bf16x8 v; } B;
        B.u[0] = __builtin_amdgcn_perm(__float_as_uint(ekk * hv[1]), __float_as_uint(ekk * hv[0]), 0x07060302u);
        B.u[1] = __builtin_amdgcn_perm(__float_as_uint(ekk * hv[3]), __float_as_uint(ekk * hv[2]), 0x07060302u);
        B.u[2] = __builtin_amdgcn_perm(__float_as_uint(ekk * hv[5]), __float_as_uint(ekk * hv[4]), 0x07060302u);
        B.u[3] = __builtin_amdgcn_perm(__float_as_uint(ekk * hv[7]), __float_as_uint(ekk * hv[6]), 0x07060302u);
        bf16x8 A0 = *(const bf16x8*)(Wfz + (k * 2)     * 256 + lane * 4);
        bf16x8 A1 = *(const bf16x8*)(Wfz + (k * 2 + 1) * 256 + lane * 4);
        acc0 = __builtin_amdgcn_mfma_f32_16x16x32_bf16(A0, B.v, acc0, 0, 0, 0);
        acc1 = __builtin_amdgcn_mfma_f32_16x16x32_bf16(A1, B.v, acc1, 0, 0, 0);
    }

    // C layout: col = lane&15 = edge, row = chunk*4 + reg = output
    if (ev) {
        int p = perm[e];
        int r = chunk * 4;
        *(f32x4*)(m + (size_t)p * 32 + r)      = acc0;
        *(f32x4*)(m + (size_t)p * 32 + 16 + r) = acc1;
    }
}

// 8 threads/node, 64 nodes/block (512 thr): hpre = bias + norm(h)@root + CSR message rows
__global__ __launch_bounds__(512) void k_agg(
    const float* __restrict__ h, const float* __restrict__ m,
    const int* __restrict__ rowptr,
    const float* __restrict__ root, const float* __restrict__ bias,
    const float* __restrict__ stats_prev, const float* __restrict__ gamma,
    const float* __restrict__ beta, int flag,
    float* __restrict__ hpre, float* __restrict__ stats_out)
{
    __shared__ float sc[32], sh[32];
    bn_scsh(stats_prev, gamma, beta, flag, sc, sh);
    __syncthreads();

    int t = threadIdx.x;
    int v = blockIdx.x * 64 + (t >> 3);
    int cg = t & 7;
    float4 acc = make_float4(0.f, 0.f, 0.f, 0.f);

    if (v < NN) {
        float hn[32];
        const float4* hp = (const float4*)(h + v * 32);
#pragma unroll
        for (int q = 0; q < 8; ++q) {
            float4 tt = hp[q];
            hn[4 * q] = tt.x; hn[4 * q + 1] = tt.y; hn[4 * q + 2] = tt.z; hn[4 * q + 3] = tt.w;
        }
        if (flag) {
#pragma unroll
            for (int i = 0; i < 32; ++i) {
                float y = fmaf(hn[i], sc[i], sh[i]);
                hn[i] = y > 0.f ? y : SLOPE * y;
            }
        }
        acc = ((const float4*)bias)[cg];
#pragma unroll
        for (int i = 0; i < 32; ++i) {
            float4 r = ((const float4*)(root + i * 32))[cg];
            acc.x = fmaf(hn[i], r.x, acc.x);
            acc.y = fmaf(hn[i], r.y, acc.y);
            acc.z = fmaf(hn[i], r.z, acc.z);
            acc.w = fmaf(hn[i], r.w, acc.w);
        }
        int q0 = rowptr[v], q1 = rowptr[v + 1];
        float4 acc2 = make_float4(0.f, 0.f, 0.f, 0.f);
        int p = q0;
        for (; p + 1 < q1; p += 2) {
            float4 t0 = ((const float4*)(m + (size_t)p * 32))[cg];
            float4 t1 = ((const float4*)(m + (size_t)(p + 1) * 32))[cg];
            acc.x += t0.x; acc.y += t0.y; acc.z += t0.z; acc.w += t0.w;
            acc2.x += t1.x; acc2.y += t1.y; acc2.z += t1.z; acc2.w += t1.w;
        }
        if (p < q1) {
            float4 t0 = ((const float4*)(m + (size_t)p * 32))[cg];
            acc.x += t0.x; acc.y += t0.y; acc.z += t0.z; acc.w += t0.w;
        }
        acc.x += acc2.x; acc.y += acc2.y; acc.z += acc2.z; acc.w += acc2.w;
        ((float4*)(hpre + v * 32))[cg] = acc;
    }

    // BN stats: butterfly over 8 nodes/wave, LDS reduce over 8 waves, 64 atomics/block
    float ss[8] = { acc.x, acc.y, acc.z, acc.w,
                    acc.x * acc.x, acc.y * acc.y, acc.z * acc.z, acc.w * acc.w };
#pragma unroll
    for (int d = 8; d < 64; d <<= 1) {
#pragma unroll
        for (int j = 0; j < 8; ++j) ss[j] += __shfl_xor(ss[j], d);
    }
    __shared__ float ls[2][8][8][4];
    int wave = t >> 6, lane = t & 63;
    if (lane < 8) {
#pragma unroll
        for (int j = 0; j < 4; ++j) {
            ls[0][wave][lane][j] = ss[j];
            ls[1][wave][lane][j] = ss[4 + j];
        }
    }
    __syncthreads();
    if (t < 64) {
        int stat = t >> 5, idx = t & 31;
        int cgg = idx >> 2, ch = idx & 3;
        float val = 0.f;
#pragma unroll
        for (int wv = 0; wv < 8; ++wv) val += ls[stat][wv][cgg][ch];
        unsafeAtomicAdd(&stats_out[stat * 32 + idx], val);
    }
}

// final-layer norm fused
__global__ __launch_bounds__(256) void k_logits(const float* __restrict__ h,
                                                const float* __restrict__ fcW,
                                                const float* __restrict__ fcb,
                                                const float* __restrict__ stats,
                                                const float* __restrict__ gamma,
                                                const float* __restrict__ beta,
                                                float* __restrict__ out) {
    __shared__ float sc[32], sh[32];
    bn_scsh(stats, gamma, beta, 1, sc, sh);
    __syncthreads();

    int v = blockIdx.x * blockDim.x + threadIdx.x;
    if (v >= NN) return;
    float hv[32];
    const float4* hp = (const float4*)(h + v * 32);
#pragma unroll
    for (int q = 0; q < 8; ++q) {
        float4 t = hp[q];
        hv[4 * q] = t.x; hv[4 * q + 1] = t.y; hv[4 * q + 2] = t.z; hv[4 * q + 3] = t.w;
    }
#pragma unroll
    for (int i = 0; i < 32; ++i) {
        float y = fmaf(hv[i], sc[i], sh[i]);
        hv[i] = y > 0.f ? y : SLOPE * y;
    }
    float lg[13];
#pragma unroll
    for (int c = 0; c < 13; ++c) lg[c] = fcb[c];
#pragma unroll
    for (int i = 0; i < 32; ++i) {
        float z = hv[i];
#pragma unroll
        for (int c = 0; c < 13; ++c) lg[c] = fmaf(z, fcW[i * 13 + c], lg[c]);
    }
    float mx = lg[0];
#pragma unroll
    for (int c = 1; c < 13; ++c) mx = fmaxf(mx, lg[c]);
    float sum = 0.0f;
#pragma unroll
    for (int c = 0; c < 13; ++c) sum += expf(lg[c] - mx);
    float lse = mx + logf(sum);
#pragma unroll
    for (int c = 0; c < 13; ++c) out[v * 13 + c] = lg[c] - lse;
}

// ---------------- launch ----------------
extern "C" void kernel_launch(void* const* d_in, const int* in_sizes, int n_in,
                              void* d_out, int out_size, void* d_ws, size_t ws_size,
                              hipStream_t stream) {
    const float* x     = (const float*)d_in[0];
    const int*   ei    = (const int*)  d_in[1];
    const float* ea    = (const float*)d_in[2];
    const float* netW1 = (const float*)d_in[3];
    const float* netb1 = (const float*)d_in[4];
    const float* netW2 = (const float*)d_in[5];
    const float* netb2 = (const float*)d_in[6];
    const float* root  = (const float*)d_in[7];
    const float* cbias = (const float*)d_in[8];
    const float* gamma = (const float*)d_in[9];
    const float* beta  = (const float*)d_in[10];
    const float* fcW   = (const float*)d_in[11];
    const float* fcb   = (const float*)d_in[12];
    float* out = (float*)d_out;

    char* w = (char*)d_ws;
    float*    m      = (float*)   (w);                 // 19,200,000 B
    float*    hA     = (float*)   (w + 19200000);      //  6,400,000 B
    float*    hB     = (float*)   (w + 25600000);      //  6,400,000 B
    int*      rowptr = (int*)     (w + 32000000);      //    200,064 B
    int*      cursor = (int*)     (w + 32200064);      //    200,064 B
    int*      perm   = (int*)     (w + 32400128);      //    600,000 B
    float*    stats  = (float*)   (w + 33000128);      //        768 B
    int*      bsum   = (int*)     (w + 33000896);      //      1,024 B
    unsigned* Wfz    = (unsigned*)(w + 33001920);      //     67,584 B
    int*      cnt    = (int*)w;                        // overlaps m (used only before m is written)

    hipMemsetAsync(cnt, 0, (NN + 1) * sizeof(int), stream);
    hipMemsetAsync(stats, 0, 768, stream);

    k_wprep<<<dim3(22, 3), 256, 0, stream>>>(netW2, netb2, Wfz);
    k_count<<<(EE + 255) / 256, 256, 0, stream>>>(ei, cnt);
    k_scanA<<<SCAN_B, 256, 0, stream>>>(cnt, rowptr, bsum);
    k_scanB<<<1, 256, 0, stream>>>(bsum);
    k_scanC<<<SCAN_B, 256, 0, stream>>>(rowptr, cursor, bsum);
    k_fill <<<(EE + 255) / 256, 256, 0, stream>>>(ei, cursor, perm);

    const float* hcur = x;
    float* bufs[2] = { hA, hB };
    for (int i = 0; i < 3; ++i) {
        float* hnext = bufs[i & 1];
        const float* stprev = stats + (i - 1) * 64;   // unused when i==0
        k_msg<<<MSG_B, 256, 0, stream>>>(
            hcur, ei, ea, netW1 + i * 20, netb1 + i * 10, Wfz + i * 5632,
            stprev, gamma + (i - 1) * 32, beta + (i - 1) * 32, i > 0, perm, m);
        k_agg<<<AGG_B, 512, 0, stream>>>(
            hcur, m, rowptr, root + i * 1024, cbias + i * 32,
            stprev, gamma + (i - 1) * 32, beta + (i - 1) * 32, i > 0,
            hnext, stats + i * 64);
        hcur = hnext;
    }
    k_logits<<<(NN + 255) / 256, 256, 0, stream>>>(
        hcur, fcW, fcb, stats + 2 * 64, gamma + 2 * 32, beta + 2 * 32, out);
}

// Round 12
// 257.414 us; speedup vs baseline: 3.0662x; 1.0113x over previous
//
#include <hip/hip_runtime.h>

#define NN 50000
#define EE 150000
#define BN_EPS 1e-5f
#define SLOPE 0.01f
#define SCAN_B 196          // ceil((NN+1)/256)
#define AGG_B  782          // ceil(NN/64)
#define MSG_B  2344         // ceil(EE/64)
#define CAP    344          // staged m rows per agg block (avg span 192; Poisson tail ~11 sigma)

typedef __attribute__((ext_vector_type(8))) short bf16x8;
typedef __attribute__((ext_vector_type(4))) float f32x4;

// ---------------- CSR build ----------------
__global__ __launch_bounds__(256) void k_count(const int* __restrict__ ei, int* __restrict__ cnt) {
    int e = blockIdx.x * blockDim.x + threadIdx.x;
    if (e < EE) atomicAdd(&cnt[ei[EE + e]], 1);
}

__global__ __launch_bounds__(256) void k_scanA(const int* __restrict__ cnt,
                                               int* __restrict__ rowptr,
                                               int* __restrict__ bsum) {
    __shared__ int buf[256];
    int t = threadIdx.x;
    int idx = blockIdx.x * 256 + t;
    int v = (idx <= NN) ? cnt[idx] : 0;
    buf[t] = v;
    __syncthreads();
    for (int off = 1; off < 256; off <<= 1) {
        int add = (t >= off) ? buf[t - off] : 0;
        __syncthreads();
        buf[t] += add;
        __syncthreads();
    }
    if (idx <= NN) rowptr[idx] = buf[t] - v;
    if (t == 255) bsum[blockIdx.x] = buf[255];
}

__global__ __launch_bounds__(256) void k_scanB(int* __restrict__ bsum) {
    __shared__ int buf[256];
    int t = threadIdx.x;
    int v = (t < SCAN_B) ? bsum[t] : 0;
    buf[t] = v;
    __syncthreads();
    for (int off = 1; off < 256; off <<= 1) {
        int add = (t >= off) ? buf[t - off] : 0;
        __syncthreads();
        buf[t] += add;
        __syncthreads();
    }
    if (t < SCAN_B) bsum[t] = buf[t] - v;
}

__global__ __launch_bounds__(256) void k_scanC(int* __restrict__ rowptr,
                                               int* __restrict__ cursor,
                                               const int* __restrict__ bsum) {
    int idx = blockIdx.x * 256 + threadIdx.x;
    if (idx <= NN) {
        int r = rowptr[idx] + bsum[blockIdx.x];
        rowptr[idx] = r;
        cursor[idx] = r;
    }
}

__global__ __launch_bounds__(256) void k_fill(const int* __restrict__ ei,
                                              int* __restrict__ cursor,
                                              int* __restrict__ perm) {
    int e = blockIdx.x * blockDim.x + threadIdx.x;
    if (e < EE) perm[e] = atomicAdd(&cursor[ei[EE + e]], 1);
}

// pre-swizzle Wf = [W2 k=0..9 ; b2] into bf16 A-fragment order
__global__ __launch_bounds__(256) void k_wprep(const float* __restrict__ netW2,
                                               const float* __restrict__ netb2,
                                               unsigned* __restrict__ Wfz) {
    int layer = blockIdx.y;
    int idx = blockIdx.x * 256 + threadIdx.x;      // < 5632
    if (idx >= 5632) return;
    const float* W2 = netW2 + layer * 10240;
    const float* b2 = netb2 + layer * 1024;
    int frag = idx >> 8;
    int rem  = idx & 255;
    int lane = rem >> 2;
    int j0   = (rem & 3) * 2;
    int tile = frag & 1;
    int kstep = frag >> 1;
    int o  = tile * 16 + (lane & 15);
    int kk = kstep * 32 + (lane >> 4) * 8 + j0;
    float v0, v1;
    if (kk < 320) {
        int base = (kk >> 5) * 1024 + (kk & 31) * 32 + o;
        v0 = W2[base];
        v1 = W2[base + 32];
    } else {
        int base = (kk - 320) * 32 + o;
        v0 = b2[base];
        v1 = b2[base + 32];
    }
    Wfz[layer * 5632 + idx] =
        __builtin_amdgcn_perm(__float_as_uint(v1), __float_as_uint(v0), 0x07060302u);
}

// in-block BN finalize: stats -> scale/shift in LDS (caller syncs)
__device__ __forceinline__ void bn_scsh(const float* __restrict__ stats,
                                        const float* __restrict__ gamma,
                                        const float* __restrict__ beta,
                                        int flag, float* sc, float* sh) {
    if (flag && threadIdx.x < 32) {
        int o = threadIdx.x;
        float mu = stats[o] * (1.0f / NN);
        float var = stats[32 + o] * (1.0f / NN) - mu * mu;
        float s = gamma[o] * rsqrtf(var + BN_EPS);
        sc[o] = s;
        sh[o] = fmaf(-mu, s, beta[o]);
    }
}

// ---------------- per-layer kernels ----------------
// LDS-free, barrier-free MFMA message kernel. 64 edges/block, 4 waves x 16 edges.
__global__ __launch_bounds__(256) void k_msg(
    const float* __restrict__ h, const int* __restrict__ ei,
    const float* __restrict__ ea, const float* __restrict__ W1,
    const float* __restrict__ b1, const unsigned* __restrict__ Wfz,
    const float* __restrict__ stats, const float* __restrict__ gamma,
    const float* __restrict__ beta, int flag,
    const int* __restrict__ perm, float* __restrict__ m)
{
    int t = threadIdx.x;
    int lane = t & 63;
    int w = t >> 6;
    int col = lane & 15;
    int chunk = lane >> 4;                 // B-frag k-chunk
    int e = blockIdx.x * 64 + w * 16 + col;
    bool ev = e < EE;
    int s = ev ? ei[e] : 0;
    float2 a = ev ? ((const float2*)ea)[e] : make_float2(0.f, 0.f);

    float hv[8];
    *(float4*)&hv[0] = *(const float4*)(h + s * 32 + chunk * 8);
    *(float4*)&hv[4] = *(const float4*)(h + s * 32 + chunk * 8 + 4);

    if (flag) {
        int i0 = chunk * 8;
#pragma unroll
        for (int j = 0; j < 8; ++j) {
            int ch = i0 + j;
            float mu = stats[ch] * (1.0f / NN);
            float var = stats[32 + ch] * (1.0f / NN) - mu * mu;
            float scv = gamma[ch] * rsqrtf(var + BN_EPS);
            float shv = fmaf(-mu, scv, beta[ch]);
            float y = fmaf(hv[j], scv, shv);
            hv[j] = y > 0.f ? y : SLOPE * y;
        }
    }

    float ekv[11];
#pragma unroll
    for (int k = 0; k < 10; ++k)
        ekv[k] = fmaxf(fmaf(a.x, W1[k], fmaf(a.y, W1[10 + k], b1[k])), 0.0f);
    ekv[10] = 1.0f;

    f32x4 acc0 = {0.f, 0.f, 0.f, 0.f};
    f32x4 acc1 = {0.f, 0.f, 0.f, 0.f};
#pragma unroll
    for (int k = 0; k < 11; ++k) {
        float ekk = ekv[k];
        union { unsigned u[4]; bf16x8 v; } B;
        B.u[0] = __builtin_amdgcn_perm(__float_as_uint(ekk * hv[1]), __float_as_uint(ekk * hv[0]), 0x07060302u);
        B.u[1] = __builtin_amdgcn_perm(__float_as_uint(ekk * hv[3]), __float_as_uint(ekk * hv[2]), 0x07060302u);
        B.u[2] = __builtin_amdgcn_perm(__float_as_uint(ekk * hv[5]), __float_as_uint(ekk * hv[4]), 0x07060302u);
        B.u[3] = __builtin_amdgcn_perm(__float_as_uint(ekk * hv[7]), __float_as_uint(ekk * hv[6]), 0x07060302u);
        bf16x8 A0 = *(const bf16x8*)(Wfz + (k * 2)     * 256 + lane * 4);
        bf16x8 A1 = *(const bf16x8*)(Wfz + (k * 2 + 1) * 256 + lane * 4);
        acc0 = __builtin_amdgcn_mfma_f32_16x16x32_bf16(A0, B.v, acc0, 0, 0, 0);
        acc1 = __builtin_amdgcn_mfma_f32_16x16x32_bf16(A1, B.v, acc1, 0, 0, 0);
    }

    if (ev) {
        int p = perm[e];
        int r = chunk * 4;
        *(f32x4*)(m + (size_t)p * 32 + r)      = acc0;
        *(f32x4*)(m + (size_t)p * 32 + 16 + r) = acc1;
    }
}

// 8 threads/node, 64 nodes/block: block's CSR span of m staged to LDS via coalesced
// streaming loads (rows padded to 36 floats -> conflict-free per-node reads).
__global__ __launch_bounds__(512) void k_agg(
    const float* __restrict__ h, const float* __restrict__ m,
    const int* __restrict__ rowptr,
    const float* __restrict__ root, const float* __restrict__ bias,
    const float* __restrict__ stats_prev, const float* __restrict__ gamma,
    const float* __restrict__ beta, int flag,
    float* __restrict__ hpre, float* __restrict__ stats_out)
{
    __shared__ float smb[CAP * 36];      // 49.5 KB staged message rows
    __shared__ float sc[32], sh[32];
    __shared__ float ls[2][8][8][4];

    bn_scsh(stats_prev, gamma, beta, flag, sc, sh);

    int t = threadIdx.x;
    int v0 = blockIdx.x * 64;
    int vend = v0 + 64 < NN ? v0 + 64 : NN;
    int p_start = rowptr[v0];
    int span = rowptr[vend] - p_start;
    int nstage = span < CAP ? span : CAP;

    for (int idx = t; idx < nstage * 8; idx += 512) {
        int r = idx >> 3, j = idx & 7;
        *(float4*)&smb[r * 36 + j * 4] = ((const float4*)m)[(size_t)(p_start + r) * 8 + j];
    }
    __syncthreads();

    int v = v0 + (t >> 3);
    int cg = t & 7;
    float4 acc = make_float4(0.f, 0.f, 0.f, 0.f);

    if (v < NN) {
        float hn[32];
        const float4* hp = (const float4*)(h + v * 32);
#pragma unroll
        for (int q = 0; q < 8; ++q) {
            float4 tt = hp[q];
            hn[4 * q] = tt.x; hn[4 * q + 1] = tt.y; hn[4 * q + 2] = tt.z; hn[4 * q + 3] = tt.w;
        }
        if (flag) {
#pragma unroll
            for (int i = 0; i < 32; ++i) {
                float y = fmaf(hn[i], sc[i], sh[i]);
                hn[i] = y > 0.f ? y : SLOPE * y;
            }
        }
        acc = ((const float4*)bias)[cg];
#pragma unroll
        for (int i = 0; i < 32; ++i) {
            float4 r = ((const float4*)(root + i * 32))[cg];
            acc.x = fmaf(hn[i], r.x, acc.x);
            acc.y = fmaf(hn[i], r.y, acc.y);
            acc.z = fmaf(hn[i], r.z, acc.z);
            acc.w = fmaf(hn[i], r.w, acc.w);
        }
        int q0 = rowptr[v] - p_start, q1 = rowptr[v + 1] - p_start;
        for (int p = q0; p < q1; ++p) {
            float4 tt;
            if (p < CAP) tt = *(const float4*)&smb[p * 36 + cg * 4];
            else         tt = ((const float4*)m)[(size_t)(p_start + p) * 8 + cg];
            acc.x += tt.x; acc.y += tt.y; acc.z += tt.z; acc.w += tt.w;
        }
        ((float4*)(hpre + v * 32))[cg] = acc;
    }

    // BN stats: butterfly over 8 nodes/wave, LDS reduce over 8 waves, 64 atomics/block
    float ss[8] = { acc.x, acc.y, acc.z, acc.w,
                    acc.x * acc.x, acc.y * acc.y, acc.z * acc.z, acc.w * acc.w };
#pragma unroll
    for (int d = 8; d < 64; d <<= 1) {
#pragma unroll
        for (int j = 0; j < 8; ++j) ss[j] += __shfl_xor(ss[j], d);
    }
    int wave = t >> 6, lane = t & 63;
    if (lane < 8) {
#pragma unroll
        for (int j = 0; j < 4; ++j) {
            ls[0][wave][lane][j] = ss[j];
            ls[1][wave][lane][j] = ss[4 + j];
        }
    }
    __syncthreads();
    if (t < 64) {
        int stat = t >> 5, idx = t & 31;
        int cgg = idx >> 2, ch = idx & 3;
        float val = 0.f;
#pragma unroll
        for (int wv = 0; wv < 8; ++wv) val += ls[stat][wv][cgg][ch];
        unsafeAtomicAdd(&stats_out[stat * 32 + idx], val);
    }
}

// final-layer norm fused
__global__ __launch_bounds__(256) void k_logits(const float* __restrict__ h,
                                                const float* __restrict__ fcW,
                                                const float* __restrict__ fcb,
                                                const float* __restrict__ stats,
                                                const float* __restrict__ gamma,
                                                const float* __restrict__ beta,
                                                float* __restrict__ out) {
    __shared__ float sc[32], sh[32];
    bn_scsh(stats, gamma, beta, 1, sc, sh);
    __syncthreads();

    int v = blockIdx.x * blockDim.x + threadIdx.x;
    if (v >= NN) return;
    float hv[32];
    const float4* hp = (const float4*)(h + v * 32);
#pragma unroll
    for (int q = 0; q < 8; ++q) {
        float4 t = hp[q];
        hv[4 * q] = t.x; hv[4 * q + 1] = t.y; hv[4 * q + 2] = t.z; hv[4 * q + 3] = t.w;
    }
#pragma unroll
    for (int i = 0; i < 32; ++i) {
        float y = fmaf(hv[i], sc[i], sh[i]);
        hv[i] = y > 0.f ? y : SLOPE * y;
    }
    float lg[13];
#pragma unroll
    for (int c = 0; c < 13; ++c) lg[c] = fcb[c];
#pragma unroll
    for (int i = 0; i < 32; ++i) {
        float z = hv[i];
#pragma unroll
        for (int c = 0; c < 13; ++c) lg[c] = fmaf(z, fcW[i * 13 + c], lg[c]);
    }
    float mx = lg[0];
#pragma unroll
    for (int c = 1; c < 13; ++c) mx = fmaxf(mx, lg[c]);
    float sum = 0.0f;
#pragma unroll
    for (int c = 0; c < 13; ++c) sum += expf(lg[c] - mx);
    float lse = mx + logf(sum);
#pragma unroll
    for (int c = 0; c < 13; ++c) out[v * 13 + c] = lg[c] - lse;
}

// ---------------- launch ----------------
extern "C" void kernel_launch(void* const* d_in, const int* in_sizes, int n_in,
                              void* d_out, int out_size, void* d_ws, size_t ws_size,
                              hipStream_t stream) {
    const float* x     = (const float*)d_in[0];
    const int*   ei    = (const int*)  d_in[1];
    const float* ea    = (const float*)d_in[2];
    const float* netW1 = (const float*)d_in[3];
    const float* netb1 = (const float*)d_in[4];
    const float* netW2 = (const float*)d_in[5];
    const float* netb2 = (const float*)d_in[6];
    const float* root  = (const float*)d_in[7];
    const float* cbias = (const float*)d_in[8];
    const float* gamma = (const float*)d_in[9];
    const float* beta  = (const float*)d_in[10];
    const float* fcW   = (const float*)d_in[11];
    const float* fcb   = (const float*)d_in[12];
    float* out = (float*)d_out;

    char* w = (char*)d_ws;
    float*    m      = (float*)   (w);                 // 19,200,000 B
    float*    hA     = (float*)   (w + 19200000);      //  6,400,000 B
    float*    hB     = (float*)   (w + 25600000);      //  6,400,000 B
    int*      rowptr = (int*)     (w + 32000000);      //    200,064 B
    int*      cursor = (int*)     (w + 32200064);      //    200,064 B
    int*      perm   = (int*)     (w + 32400128);      //    600,000 B
    float*    stats  = (float*)   (w + 33000128);      //        768 B
    int*      bsum   = (int*)     (w + 33000896);      //      1,024 B
    unsigned* Wfz    = (unsigned*)(w + 33001920);      //     67,584 B
    int*      cnt    = (int*)w;                        // overlaps m (used only before m is written)

    hipMemsetAsync(cnt, 0, (NN + 1) * sizeof(int), stream);
    hipMemsetAsync(stats, 0, 768, stream);

    k_wprep<<<dim3(22, 3), 256, 0, stream>>>(netW2, netb2, Wfz);
    k_count<<<(EE + 255) / 256, 256, 0, stream>>>(ei, cnt);
    k_scanA<<<SCAN_B, 256, 0, stream>>>(cnt, rowptr, bsum);
    k_scanB<<<1, 256, 0, stream>>>(bsum);
    k_scanC<<<SCAN_B, 256, 0, stream>>>(rowptr, cursor, bsum);
    k_fill <<<(EE + 255) / 256, 256, 0, stream>>>(ei, cursor, perm);

    const float* hcur = x;
    float* bufs[2] = { hA, hB };
    for (int i = 0; i < 3; ++i) {
        float* hnext = bufs[i & 1];
        const float* stprev = stats + (i - 1) * 64;   // unused when i==0
        k_msg<<<MSG_B, 256, 0, stream>>>(
            hcur, ei, ea, netW1 + i * 20, netb1 + i * 10, Wfz + i * 5632,
            stprev, gamma + (i - 1) * 32, beta + (i - 1) * 32, i > 0, perm, m);
        k_agg<<<AGG_B, 512, 0, stream>>>(
            hcur, m, rowptr, root + i * 1024, cbias + i * 32,
            stprev, gamma + (i - 1) * 32, beta + (i - 1) * 32, i > 0,
            hnext, stats + i * 64);
        hcur = hnext;
    }
    k_logits<<<(NN + 255) / 256, 256, 0, stream>>>(
        hcur, fcW, fcb, stats + 2 * 64, gamma + 2 * 32, beta + 2 * 32, out);
}

// Round 13
// 252.961 us; speedup vs baseline: 3.1201x; 1.0176x over previous
//
#include <hip/hip_runtime.h>

#define NN 50000
#define EE 150000
#define BN_EPS 1e-5f
#define SLOPE 0.01f
#define SCAN_B 196          // ceil((NN+1)/256)
#define AGG_B  782          // ceil(NN/64)
#define CAP    344          // staged message rows per block chunk (avg span 192; ~11 sigma)

typedef __attribute__((ext_vector_type(8))) short bf16x8;
typedef __attribute__((ext_vector_type(4))) float f32x4;

// ---------------- CSR build ----------------
__global__ __launch_bounds__(256) void k_count(const int* __restrict__ ei, int* __restrict__ cnt) {
    int e = blockIdx.x * blockDim.x + threadIdx.x;
    if (e < EE) atomicAdd(&cnt[ei[EE + e]], 1);
}

__global__ __launch_bounds__(256) void k_scanA(const int* __restrict__ cnt,
                                               int* __restrict__ rowptr,
                                               int* __restrict__ bsum) {
    __shared__ int buf[256];
    int t = threadIdx.x;
    int idx = blockIdx.x * 256 + t;
    int v = (idx <= NN) ? cnt[idx] : 0;
    buf[t] = v;
    __syncthreads();
    for (int off = 1; off < 256; off <<= 1) {
        int add = (t >= off) ? buf[t - off] : 0;
        __syncthreads();
        buf[t] += add;
        __syncthreads();
    }
    if (idx <= NN) rowptr[idx] = buf[t] - v;
    if (t == 255) bsum[blockIdx.x] = buf[255];
}

__global__ __launch_bounds__(256) void k_scanB(int* __restrict__ bsum) {
    __shared__ int buf[256];
    int t = threadIdx.x;
    int v = (t < SCAN_B) ? bsum[t] : 0;
    buf[t] = v;
    __syncthreads();
    for (int off = 1; off < 256; off <<= 1) {
        int add = (t >= off) ? buf[t - off] : 0;
        __syncthreads();
        buf[t] += add;
        __syncthreads();
    }
    if (t < SCAN_B) bsum[t] = buf[t] - v;
}

__global__ __launch_bounds__(256) void k_scanC(int* __restrict__ rowptr,
                                               int* __restrict__ cursor,
                                               const int* __restrict__ bsum) {
    int idx = blockIdx.x * 256 + threadIdx.x;
    if (idx <= NN) {
        int r = rowptr[idx] + bsum[blockIdx.x];
        rowptr[idx] = r;
        cursor[idx] = r;
    }
}

// eids[slot] = edge id (slots grouped by dst, contiguous per node)
__global__ __launch_bounds__(256) void k_fill(const int* __restrict__ ei,
                                              int* __restrict__ cursor,
                                              int* __restrict__ eids) {
    int e = blockIdx.x * blockDim.x + threadIdx.x;
    if (e < EE) {
        int pos = atomicAdd(&cursor[ei[EE + e]], 1);
        eids[pos] = e;
    }
}

// pre-swizzle Wf = [W2 k=0..9 ; b2] into bf16 A-fragment order
__global__ __launch_bounds__(256) void k_wprep(const float* __restrict__ netW2,
                                               const float* __restrict__ netb2,
                                               unsigned* __restrict__ Wfz) {
    int layer = blockIdx.y;
    int idx = blockIdx.x * 256 + threadIdx.x;      // < 5632
    if (idx >= 5632) return;
    const float* W2 = netW2 + layer * 10240;
    const float* b2 = netb2 + layer * 1024;
    int frag = idx >> 8;
    int rem  = idx & 255;
    int lane = rem >> 2;
    int j0   = (rem & 3) * 2;
    int tile = frag & 1;
    int kstep = frag >> 1;
    int o  = tile * 16 + (lane & 15);
    int kk = kstep * 32 + (lane >> 4) * 8 + j0;
    float v0, v1;
    if (kk < 320) {
        int base = (kk >> 5) * 1024 + (kk & 31) * 32 + o;
        v0 = W2[base];
        v1 = W2[base + 32];
    } else {
        int base = (kk - 320) * 32 + o;
        v0 = b2[base];
        v1 = b2[base + 32];
    }
    Wfz[layer * 5632 + idx] =
        __builtin_amdgcn_perm(__float_as_uint(v1), __float_as_uint(v0), 0x07060302u);
}

// in-block BN finalize: stats -> scale/shift in LDS (caller syncs)
__device__ __forceinline__ void bn_scsh(const float* __restrict__ stats,
                                        const float* __restrict__ gamma,
                                        const float* __restrict__ beta,
                                        int flag, float* sc, float* sh) {
    if (flag && threadIdx.x < 32) {
        int o = threadIdx.x;
        float mu = stats[o] * (1.0f / NN);
        float var = stats[32 + o] * (1.0f / NN) - mu * mu;
        float s = gamma[o] * rsqrtf(var + BN_EPS);
        sc[o] = s;
        sh[o] = fmaf(-mu, s, beta[o]);
    }
}

// ---------------- fused per-layer kernel ----------------
// Block = 64 nodes + their contiguous CSR slot span (~192 edges).
// Phase 1: root term per node. Phase 2 (per chunk): MFMA messages -> LDS, sync,
// per-node sum from LDS. No global m buffer. BN stats tail unchanged.
__global__ __launch_bounds__(512) void k_layer(
    const float* __restrict__ h, const int* __restrict__ ei,
    const float* __restrict__ ea, const float* __restrict__ W1,
    const float* __restrict__ b1, const unsigned* __restrict__ Wfz,
    const int* __restrict__ rowptr, const int* __restrict__ eids,
    const float* __restrict__ root, const float* __restrict__ bias,
    const float* __restrict__ stats_prev, const float* __restrict__ gamma,
    const float* __restrict__ beta, int flag,
    float* __restrict__ hpre, float* __restrict__ stats_out)
{
    __shared__ float smb[CAP * 36];      // 49.5 KB staged message rows (36-float pad)
    __shared__ float sc[32], sh[32];
    __shared__ float ls[2][8][8][4];

    int t = threadIdx.x;
    bn_scsh(stats_prev, gamma, beta, flag, sc, sh);
    __syncthreads();

    int v0 = blockIdx.x * 64;
    int vend = v0 + 64 < NN ? v0 + 64 : NN;
    int p_start = rowptr[v0];
    int span = rowptr[vend] - p_start;

    int v = v0 + (t >> 3);
    int cg = t & 7;
    float4 acc = make_float4(0.f, 0.f, 0.f, 0.f);

    // ---- phase 1: bias + norm(h[v]) @ root ----
    if (v < NN) {
        float hn[32];
        const float4* hp = (const float4*)(h + v * 32);
#pragma unroll
        for (int q = 0; q < 8; ++q) {
            float4 tt = hp[q];
            hn[4 * q] = tt.x; hn[4 * q + 1] = tt.y; hn[4 * q + 2] = tt.z; hn[4 * q + 3] = tt.w;
        }
        if (flag) {
#pragma unroll
            for (int i = 0; i < 32; ++i) {
                float y = fmaf(hn[i], sc[i], sh[i]);
                hn[i] = y > 0.f ? y : SLOPE * y;
            }
        }
        acc = ((const float4*)bias)[cg];
#pragma unroll
        for (int i = 0; i < 32; ++i) {
            float4 r = ((const float4*)(root + i * 32))[cg];
            acc.x = fmaf(hn[i], r.x, acc.x);
            acc.y = fmaf(hn[i], r.y, acc.y);
            acc.z = fmaf(hn[i], r.z, acc.z);
            acc.w = fmaf(hn[i], r.w, acc.w);
        }
    }

    // ---- phase 2: chunked MFMA messages -> LDS -> per-node sum ----
    int lane = t & 63;
    int w = t >> 6;
    int col = lane & 15;
    int chunk = lane >> 4;               // B-frag k-chunk (h channels chunk*8..+7)

    for (int c0 = 0; c0 < span; c0 += CAP) {
        int csize = span - c0 < CAP ? span - c0 : CAP;

        for (int base = 0; base < csize; base += 128) {
            int sl = base + w * 16 + col;        // slot within chunk
            bool evv = sl < csize;
            int e = evv ? eids[p_start + c0 + sl] : 0;
            int s = evv ? ei[e] : 0;
            float2 a = evv ? ((const float2*)ea)[e] : make_float2(0.f, 0.f);

            float hv[8];
            *(float4*)&hv[0] = *(const float4*)(h + s * 32 + chunk * 8);
            *(float4*)&hv[4] = *(const float4*)(h + s * 32 + chunk * 8 + 4);
            if (flag) {
                int i0 = chunk * 8;
#pragma unroll
                for (int j = 0; j < 8; ++j) {
                    float y = fmaf(hv[j], sc[i0 + j], sh[i0 + j]);
                    hv[j] = y > 0.f ? y : SLOPE * y;
                }
            }

            float ekv[11];
#pragma unroll
            for (int k = 0; k < 10; ++k)
                ekv[k] = fmaxf(fmaf(a.x, W1[k], fmaf(a.y, W1[10 + k], b1[k])), 0.0f);
            ekv[10] = 1.0f;

            f32x4 acc0 = {0.f, 0.f, 0.f, 0.f};
            f32x4 acc1 = {0.f, 0.f, 0.f, 0.f};
#pragma unroll
            for (int k = 0; k < 11; ++k) {
                float ekk = ekv[k];
                union { unsigned u[4]; bf16x8 v; } B;
                B.u[0] = __builtin_amdgcn_perm(__float_as_uint(ekk * hv[1]), __float_as_uint(ekk * hv[0]), 0x07060302u);
                B.u[1] = __builtin_amdgcn_perm(__float_as_uint(ekk * hv[3]), __float_as_uint(ekk * hv[2]), 0x07060302u);
                B.u[2] = __builtin_amdgcn_perm(__float_as_uint(ekk * hv[5]), __float_as_uint(ekk * hv[4]), 0x07060302u);
                B.u[3] = __builtin_amdgcn_perm(__float_as_uint(ekk * hv[7]), __float_as_uint(ekk * hv[6]), 0x07060302u);
                bf16x8 A0 = *(const bf16x8*)(Wfz + (k * 2)     * 256 + lane * 4);
                bf16x8 A1 = *(const bf16x8*)(Wfz + (k * 2 + 1) * 256 + lane * 4);
                acc0 = __builtin_amdgcn_mfma_f32_16x16x32_bf16(A0, B.v, acc0, 0, 0, 0);
                acc1 = __builtin_amdgcn_mfma_f32_16x16x32_bf16(A1, B.v, acc1, 0, 0, 0);
            }

            // C layout: col = edge slot, row = chunk*4 + reg = output channel
            if (evv) {
                *(f32x4*)&smb[sl * 36 + chunk * 4]      = acc0;
                *(f32x4*)&smb[sl * 36 + 16 + chunk * 4] = acc1;
            }
        }
        __syncthreads();

        if (v < NN) {
            int q0 = rowptr[v] - p_start - c0;
            int q1 = rowptr[v + 1] - p_start - c0;
            q0 = q0 > 0 ? q0 : 0;
            q1 = q1 < csize ? q1 : csize;
            for (int p = q0; p < q1; ++p) {
                float4 tt = *(const float4*)&smb[p * 36 + cg * 4];
                acc.x += tt.x; acc.y += tt.y; acc.z += tt.z; acc.w += tt.w;
            }
        }
        __syncthreads();
    }

    if (v < NN) ((float4*)(hpre + v * 32))[cg] = acc;

    // ---- BN stats tail: butterfly over 8 nodes/wave, LDS reduce, 64 atomics/block ----
    float ss[8] = { acc.x, acc.y, acc.z, acc.w,
                    acc.x * acc.x, acc.y * acc.y, acc.z * acc.z, acc.w * acc.w };
#pragma unroll
    for (int d = 8; d < 64; d <<= 1) {
#pragma unroll
        for (int j = 0; j < 8; ++j) ss[j] += __shfl_xor(ss[j], d);
    }
    int wave = t >> 6, lane2 = t & 63;
    if (lane2 < 8) {
#pragma unroll
        for (int j = 0; j < 4; ++j) {
            ls[0][wave][lane2][j] = ss[j];
            ls[1][wave][lane2][j] = ss[4 + j];
        }
    }
    __syncthreads();
    if (t < 64) {
        int stat = t >> 5, idx = t & 31;
        int cgg = idx >> 2, ch = idx & 3;
        float val = 0.f;
#pragma unroll
        for (int wv = 0; wv < 8; ++wv) val += ls[stat][wv][cgg][ch];
        unsafeAtomicAdd(&stats_out[stat * 32 + idx], val);
    }
}

// final-layer norm fused
__global__ __launch_bounds__(256) void k_logits(const float* __restrict__ h,
                                                const float* __restrict__ fcW,
                                                const float* __restrict__ fcb,
                                                const float* __restrict__ stats,
                                                const float* __restrict__ gamma,
                                                const float* __restrict__ beta,
                                                float* __restrict__ out) {
    __shared__ float sc[32], sh[32];
    bn_scsh(stats, gamma, beta, 1, sc, sh);
    __syncthreads();

    int v = blockIdx.x * blockDim.x + threadIdx.x;
    if (v >= NN) return;
    float hv[32];
    const float4* hp = (const float4*)(h + v * 32);
#pragma unroll
    for (int q = 0; q < 8; ++q) {
        float4 t = hp[q];
        hv[4 * q] = t.x; hv[4 * q + 1] = t.y; hv[4 * q + 2] = t.z; hv[4 * q + 3] = t.w;
    }
#pragma unroll
    for (int i = 0; i < 32; ++i) {
        float y = fmaf(hv[i], sc[i], sh[i]);
        hv[i] = y > 0.f ? y : SLOPE * y;
    }
    float lg[13];
#pragma unroll
    for (int c = 0; c < 13; ++c) lg[c] = fcb[c];
#pragma unroll
    for (int i = 0; i < 32; ++i) {
        float z = hv[i];
#pragma unroll
        for (int c = 0; c < 13; ++c) lg[c] = fmaf(z, fcW[i * 13 + c], lg[c]);
    }
    float mx = lg[0];
#pragma unroll
    for (int c = 1; c < 13; ++c) mx = fmaxf(mx, lg[c]);
    float sum = 0.0f;
#pragma unroll
    for (int c = 0; c < 13; ++c) sum += expf(lg[c] - mx);
    float lse = mx + logf(sum);
#pragma unroll
    for (int c = 0; c < 13; ++c) out[v * 13 + c] = lg[c] - lse;
}

// ---------------- launch ----------------
extern "C" void kernel_launch(void* const* d_in, const int* in_sizes, int n_in,
                              void* d_out, int out_size, void* d_ws, size_t ws_size,
                              hipStream_t stream) {
    const float* x     = (const float*)d_in[0];
    const int*   ei    = (const int*)  d_in[1];
    const float* ea    = (const float*)d_in[2];
    const float* netW1 = (const float*)d_in[3];
    const float* netb1 = (const float*)d_in[4];
    const float* netW2 = (const float*)d_in[5];
    const float* netb2 = (const float*)d_in[6];
    const float* root  = (const float*)d_in[7];
    const float* cbias = (const float*)d_in[8];
    const float* gamma = (const float*)d_in[9];
    const float* beta  = (const float*)d_in[10];
    const float* fcW   = (const float*)d_in[11];
    const float* fcb   = (const float*)d_in[12];
    float* out = (float*)d_out;

    char* w = (char*)d_ws;
    float*    hA     = (float*)   (w);                 //  6,400,000 B
    float*    hB     = (float*)   (w +  6400000);      //  6,400,000 B
    int*      rowptr = (int*)     (w + 12800000);      //    200,064 B
    int*      cursor = (int*)     (w + 13000064);      //    200,064 B
    int*      eids   = (int*)     (w + 13200128);      //    600,000 B
    float*    stats  = (float*)   (w + 13800128);      //        768 B
    int*      bsum   = (int*)     (w + 13800896);      //      1,024 B
    unsigned* Wfz    = (unsigned*)(w + 13801920);      //     67,584 B
    int*      cnt    = (int*)     (w + 13869504);      //    200,064 B

    hipMemsetAsync(cnt, 0, (NN + 1) * sizeof(int), stream);
    hipMemsetAsync(stats, 0, 768, stream);

    k_wprep<<<dim3(22, 3), 256, 0, stream>>>(netW2, netb2, Wfz);
    k_count<<<(EE + 255) / 256, 256, 0, stream>>>(ei, cnt);
    k_scanA<<<SCAN_B, 256, 0, stream>>>(cnt, rowptr, bsum);
    k_scanB<<<1, 256, 0, stream>>>(bsum);
    k_scanC<<<SCAN_B, 256, 0, stream>>>(rowptr, cursor, bsum);
    k_fill <<<(EE + 255) / 256, 256, 0, stream>>>(ei, cursor, eids);

    const float* hcur = x;
    float* bufs[2] = { hA, hB };
    for (int i = 0; i < 3; ++i) {
        float* hnext = bufs[i & 1];
        const float* stprev = stats + (i - 1) * 64;   // unused when i==0
        k_layer<<<AGG_B, 512, 0, stream>>>(
            hcur, ei, ea, netW1 + i * 20, netb1 + i * 10, Wfz + i * 5632,
            rowptr, eids, root + i * 1024, cbias + i * 32,
            stprev, gamma + (i - 1) * 32, beta + (i - 1) * 32, i > 0,
            hnext, stats + i * 64);
        hcur = hnext;
    }
    k_logits<<<(NN + 255) / 256, 256, 0, stream>>>(
        hcur, fcW, fcb, stats + 2 * 64, gamma + 2 * 32, beta + 2 * 32, out);
}